// Round 1
// baseline (504.202 us; speedup 1.0000x reference)
//
#include <hip/hip_runtime.h>
#include <hip/hip_bf16.h>
#include <stdint.h>

typedef unsigned short u16;
typedef __attribute__((ext_vector_type(4))) float f32x4;
typedef __attribute__((ext_vector_type(8))) short bf16x8;

#define DEV __device__ __forceinline__

DEV float bf2f(u16 b){ unsigned u = ((unsigned)b) << 16; return __builtin_bit_cast(float, u); }
DEV u16 f2bf(float f){
  unsigned u = __builtin_bit_cast(unsigned, f);
  u += 0x7FFFu + ((u >> 16) & 1u);
  return (u16)(u >> 16);
}
DEV float ldf(const float* p){ return *p; }
DEV float ldf(const u16* p){ return bf2f(*p); }

// ---------------------------------------------------------------------------
// Generic 64x64-tile transpose, any->bf16: dst[c][r] = src[r][c]
// grid: (R/64, C/64, batch), block 256
template<typename T>
__global__ __launch_bounds__(256) void tr_to_bf16(
    const T* __restrict__ src, u16* __restrict__ dst,
    int R, int C, long sB, long dB)
{
  __shared__ float tile[64][65];
  const int b = blockIdx.z;
  src += (long)b * sB;
  dst += (long)b * dB;
  const int r0 = blockIdx.x * 64, c0 = blockIdx.y * 64;
  const int t = threadIdx.x;
  const int rr = t >> 2, cc = (t & 3) * 16;
  const T* sp = src + (long)(r0 + rr) * C + (c0 + cc);
  #pragma unroll
  for (int q = 0; q < 16; q++) tile[rr][cc + q] = ldf(sp + q);
  __syncthreads();
  u16* dp = dst + (long)(c0 + rr) * R + (r0 + cc);
  #pragma unroll
  for (int q = 0; q < 16; q++) dp[q] = f2bf(tile[cc + q][rr]);
}

// ---------------------------------------------------------------------------
// NT GEMM tile core: C[i][j] = sum_k A[i][k] * B[j][k], A/B row-major bf16.
// Block = WR*WC waves; wave (wr,wc) owns (MF*16) x (NF*16) of the BM x BN tile.
// Staging: global_load_lds 16B, linear LDS (wave-uniform base + lane*16).
template<int BM, int BN, int BK, int WR, int WC, int MF, int NF>
DEV void gemm_nt(const u16* __restrict__ A, const u16* __restrict__ B,
                 int K, int arow0, int brow0,
                 f32x4 (&acc)[MF][NF], u16* As, u16* Bs)
{
  const int tid  = threadIdx.x;
  const int lane = tid & 63;
  const int w    = tid >> 6;
  const int wr   = w / WC, wc = w % WC;
  constexpr int NT   = WR * WC * 64;
  constexpr int AISS = (BM * BK * 2) / (NT * 16);
  constexpr int BISS = (BN * BK * 2) / (NT * 16);

  #pragma unroll
  for (int m = 0; m < MF; m++)
    #pragma unroll
    for (int n = 0; n < NF; n++) acc[m][n] = f32x4{0.f, 0.f, 0.f, 0.f};

  const int frow = lane & 15;          // fragment row (m / n index)
  const int fk   = (lane >> 4) * 8;    // fragment k offset

  for (int kt = 0; kt < K; kt += BK) {
    __syncthreads();   // previous iteration's LDS reads done
    #pragma unroll
    for (int q = 0; q < AISS; q++) {
      const int boff = q * NT * 16 + tid * 16;
      const int row  = boff / (BK * 2);
      const int kk   = (boff % (BK * 2)) >> 1;
      const u16* src = A + (long)(arow0 + row) * K + kt + kk;
      __builtin_amdgcn_global_load_lds(
          (const __attribute__((address_space(1))) void*)src,
          (__attribute__((address_space(3))) void*)(As + (boff >> 1)), 16, 0, 0);
    }
    #pragma unroll
    for (int q = 0; q < BISS; q++) {
      const int boff = q * NT * 16 + tid * 16;
      const int row  = boff / (BK * 2);
      const int kk   = (boff % (BK * 2)) >> 1;
      const u16* src = B + (long)(brow0 + row) * K + kt + kk;
      __builtin_amdgcn_global_load_lds(
          (const __attribute__((address_space(1))) void*)src,
          (__attribute__((address_space(3))) void*)(Bs + (boff >> 1)), 16, 0, 0);
    }
    asm volatile("s_waitcnt vmcnt(0)" ::: "memory");
    __syncthreads();
    #pragma unroll
    for (int ks = 0; ks < BK / 32; ++ks) {
      bf16x8 af[MF], bfr[NF];
      #pragma unroll
      for (int m = 0; m < MF; m++) {
        const int row = wr * (MF * 16) + m * 16 + frow;
        af[m] = *(const bf16x8*)(As + row * BK + ks * 32 + fk);
      }
      #pragma unroll
      for (int n = 0; n < NF; n++) {
        const int row = wc * (NF * 16) + n * 16 + frow;
        bfr[n] = *(const bf16x8*)(Bs + row * BK + ks * 32 + fk);
      }
      #pragma unroll
      for (int m = 0; m < MF; m++)
        #pragma unroll
        for (int n = 0; n < NF; n++)
          acc[m][n] = __builtin_amdgcn_mfma_f32_16x16x32_bf16(af[m], bfr[n], acc[m][n], 0, 0, 0);
    }
  }
}

// ---------------------------------------------------------------------------
// K1: proj = xt @ Wp^T + bias -> split into Q/K/V (bf16), layout [b][h][s][d]
__global__ __launch_bounds__(256) void k_proj(
    const u16* __restrict__ xt, const u16* __restrict__ Wtp,
    const float* __restrict__ bp,
    u16* __restrict__ Q, u16* __restrict__ Kb, u16* __restrict__ V)
{
  __shared__ __align__(16) u16 As[128 * 64];
  __shared__ __align__(16) u16 Bs[128 * 64];
  f32x4 acc[4][4];
  const int arow0 = blockIdx.x * 128, brow0 = blockIdx.y * 128;
  gemm_nt<128, 128, 64, 2, 2, 4, 4>(xt, Wtp, 64, arow0, brow0, acc, As, Bs);
  const int lane = threadIdx.x & 63;
  const int w = threadIdx.x >> 6;
  const int wr = w >> 1, wc = w & 1;
  const int gm0 = arow0 + wr * 64;
  const int gn0 = brow0 + wc * 64;
  #pragma unroll
  for (int m = 0; m < 4; m++)
    #pragma unroll
    for (int n = 0; n < 4; n++)
      #pragma unroll
      for (int j = 0; j < 4; j++) {
        const int gm = gm0 + m * 16 + (lane >> 4) * 4 + j;
        const int gn = gn0 + n * 16 + (lane & 15);
        const float v = acc[m][n][j] + bp[gn];
        const int b = gm >> 10, s = gm & 1023;
        const int h = gn / 1920, r = gn % 1920;
        const long base = ((long)(b * 4 + h) * 1024 + s) * 640;
        const u16 bv = f2bf(v);
        if (r < 640)       Q [base + r]        = bv;
        else if (r < 1280) Kb[base + r - 640]  = bv;
        else               V [base + r - 1280] = bv;
      }
}

// K2: S[b][h][i][j] = SCALE * sum_d Q[i,d] K[j,d]   (bf16 out)
__global__ __launch_bounds__(256) void k_qk(
    const u16* __restrict__ Q, const u16* __restrict__ Kb, u16* __restrict__ S)
{
  __shared__ __align__(16) u16 As[128 * 64];
  __shared__ __align__(16) u16 Bs[128 * 64];
  const int bh = blockIdx.z;
  f32x4 acc[4][4];
  gemm_nt<128, 128, 64, 2, 2, 4, 4>(Q + (long)bh * 655360, Kb + (long)bh * 655360, 640,
                                    blockIdx.x * 128, blockIdx.y * 128, acc, As, Bs);
  const int lane = threadIdx.x & 63;
  const int w = threadIdx.x >> 6;
  const int wr = w >> 1, wc = w & 1;
  u16* Sp = S + ((long)bh << 20);
  const int gi0 = blockIdx.x * 128 + wr * 64;
  const int gj0 = blockIdx.y * 128 + wc * 64;
  #pragma unroll
  for (int m = 0; m < 4; m++)
    #pragma unroll
    for (int n = 0; n < 4; n++)
      #pragma unroll
      for (int j = 0; j < 4; j++) {
        const int gi = gi0 + m * 16 + (lane >> 4) * 4 + j;
        const int gj = gj0 + n * 16 + (lane & 15);
        Sp[(long)gi * 1024 + gj] = f2bf(acc[m][n][j] * 0.03952847075210474f);
      }
}

// K3: column stats over i: M[j]=max_i S[i][j], Rz[j]=1/sum_i exp(S-M)
__global__ __launch_bounds__(256) void k_stats(
    const u16* __restrict__ S, float* __restrict__ Mb, float* __restrict__ Rz)
{
  const int bh = blockIdx.y;
  const int j = blockIdx.x * 256 + threadIdx.x;
  const u16* Sp = S + ((long)bh << 20) + j;
  float m = -3.0e38f;
  #pragma unroll 8
  for (int i = 0; i < 1024; i++) m = fmaxf(m, bf2f(Sp[(long)i << 10]));
  float z = 0.f;
  #pragma unroll 8
  for (int i = 0; i < 1024; i++) z += __expf(bf2f(Sp[(long)i << 10]) - m);
  Mb[bh * 1024 + j] = m;
  Rz[bh * 1024 + j] = 1.0f / z;
}

// K4: P = exp(S - M[j]) * Rz[j], in place (bf16)
__global__ __launch_bounds__(256) void k_norm(
    u16* __restrict__ S, const float* __restrict__ Mb, const float* __restrict__ Rz)
{
  const long i0 = ((long)blockIdx.x * 256 + threadIdx.x) * 8;
  const int bh = (int)(i0 >> 20);
  const int j = (int)(i0 & 1023);
  const float* Mp = Mb + bh * 1024 + j;
  const float* Rp = Rz + bh * 1024 + j;
  bf16x8 v = *(const bf16x8*)(S + i0);
  bf16x8 r;
  #pragma unroll
  for (int e = 0; e < 8; e++) {
    const float f = __expf(bf2f((u16)v[e]) - Mp[e]) * Rp[e];
    r[e] = (short)f2bf(f);
  }
  *(bf16x8*)(S + i0) = r;
}

// K5: att[b][s][h*640+d] = sum_j P[i][j] * Vt[d][j]
__global__ __launch_bounds__(256) void k_pv(
    const u16* __restrict__ P, const u16* __restrict__ Vt, u16* __restrict__ att)
{
  __shared__ __align__(16) u16 As[128 * 64];
  __shared__ __align__(16) u16 Bs[128 * 64];
  const int bh = blockIdx.z;
  f32x4 acc[4][4];
  gemm_nt<128, 128, 64, 2, 2, 4, 4>(P + ((long)bh << 20), Vt + (long)bh * 655360, 1024,
                                    blockIdx.x * 128, blockIdx.y * 128, acc, As, Bs);
  const int lane = threadIdx.x & 63;
  const int w = threadIdx.x >> 6;
  const int wr = w >> 1, wc = w & 1;
  const int b = bh >> 2, h = bh & 3;
  const int gi0 = blockIdx.x * 128 + wr * 64;
  const int gd0 = blockIdx.y * 128 + wc * 64;
  #pragma unroll
  for (int m = 0; m < 4; m++)
    #pragma unroll
    for (int n = 0; n < 4; n++)
      #pragma unroll
      for (int j = 0; j < 4; j++) {
        const int gi = gi0 + m * 16 + (lane >> 4) * 4 + j;
        const int gd = gd0 + n * 16 + (lane & 15);
        att[((long)b * 1024 + gi) * 2560 + h * 640 + gd] = f2bf(acc[m][n][j]);
      }
}

// K6: out[b][c][s] = att @ Wo^T + bo + x   (writes f32 output, fused residual)
__global__ __launch_bounds__(256) void k_out(
    const u16* __restrict__ att, const u16* __restrict__ Wot,
    const float* __restrict__ bo, const float* __restrict__ x, float* __restrict__ out)
{
  __shared__ __align__(16) u16 As[128 * 64];
  __shared__ __align__(16) u16 Bs[64 * 64];
  f32x4 acc[2][4];
  gemm_nt<128, 64, 64, 4, 1, 2, 4>(att, Wot, 2560, blockIdx.x * 128, 0, acc, As, Bs);
  const int lane = threadIdx.x & 63;
  const int wr = threadIdx.x >> 6;
  const int gm0 = blockIdx.x * 128 + wr * 32;
  #pragma unroll
  for (int m = 0; m < 2; m++)
    #pragma unroll
    for (int n = 0; n < 4; n++)
      #pragma unroll
      for (int j = 0; j < 4; j++) {
        const int gm = gm0 + m * 16 + (lane >> 4) * 4 + j;
        const int gn = n * 16 + (lane & 15);
        const int b = gm >> 10, s = gm & 1023;
        const long xi = ((long)b * 64 + gn) * 1024 + s;
        out[xi] = acc[m][n][j] + bo[gn] + x[xi];
      }
}

// ---------------------------------------------------------------------------
extern "C" void kernel_launch(void* const* d_in, const int* in_sizes, int n_in,
                              void* d_out, int out_size, void* d_ws, size_t ws_size,
                              hipStream_t stream)
{
  (void)in_sizes; (void)n_in; (void)out_size; (void)ws_size;
  const float* x  = (const float*)d_in[0];
  // d_in[1] = t (unused)
  const float* Wp = (const float*)d_in[2];
  const float* bp = (const float*)d_in[3];
  const float* Wo = (const float*)d_in[4];
  const float* bo = (const float*)d_in[5];
  float* out = (float*)d_out;

  char* w8 = (char*)d_ws;
  // byte offsets (196 MB total); att aliases Q, Vt aliases K (dead by then)
  u16* Q   = (u16*)(w8 + 0L);           // [32][1024][640] bf16, 40 MB
  u16* Kb  = (u16*)(w8 + 41943040L);    // 40 MB
  u16* V   = (u16*)(w8 + 83886080L);    // 40 MB
  u16* S   = (u16*)(w8 + 125829120L);   // [32][1024][1024] bf16, 64 MB
  u16* att = Q;                         // reuse Q space after k_qk
  u16* Vt  = Kb;                        // reuse K space after k_qk
  u16* xt  = (u16*)(w8 + 192937984L);   // [8192][64] bf16, 1 MB
  u16* Wtp = (u16*)(w8 + 193986560L);   // [7680][64] bf16
  u16* Wot = (u16*)(w8 + 194969600L);   // [64][2560] bf16
  float* Mb = (float*)(w8 + 195297280L);
  float* Rz = (float*)(w8 + 195428352L);

  // input transposes -> bf16 NT operands
  tr_to_bf16<float><<<dim3(1, 16, 8),  256, 0, stream>>>(x,  xt,  64, 1024, 65536L, 65536L);
  tr_to_bf16<float><<<dim3(1, 120, 1), 256, 0, stream>>>(Wp, Wtp, 64, 7680, 0L, 0L);
  tr_to_bf16<float><<<dim3(40, 1, 1),  256, 0, stream>>>(Wo, Wot, 2560, 64, 0L, 0L);
  // pipeline
  k_proj<<<dim3(64, 60),   256, 0, stream>>>(xt, Wtp, bp, Q, Kb, V);
  k_qk  <<<dim3(8, 8, 32), 256, 0, stream>>>(Q, Kb, S);
  tr_to_bf16<u16><<<dim3(16, 10, 32), 256, 0, stream>>>(V, Vt, 1024, 640, 655360L, 655360L);
  k_stats<<<dim3(4, 32),   256, 0, stream>>>(S, Mb, Rz);
  k_norm <<<16384,         256, 0, stream>>>(S, Mb, Rz);
  k_pv  <<<dim3(8, 5, 32), 256, 0, stream>>>(S, Vt, att);
  k_out <<<64,             256, 0, stream>>>(att, Wot, bo, x, out);
}

// Round 2
// 298.324 us; speedup vs baseline: 1.6901x; 1.6901x over previous
//
#include <hip/hip_runtime.h>
#include <hip/hip_bf16.h>
#include <stdint.h>

typedef unsigned short u16;
typedef __attribute__((ext_vector_type(4))) float f32x4;
typedef __attribute__((ext_vector_type(8))) short bf16x8;

#define DEV __device__ __forceinline__

DEV float bf2f(u16 b){ unsigned u = ((unsigned)b) << 16; return __builtin_bit_cast(float, u); }
DEV u16 f2bf(float f){
  unsigned u = __builtin_bit_cast(unsigned, f);
  u += 0x7FFFu + ((u >> 16) & 1u);
  return (u16)(u >> 16);
}
DEV float ldf(const float* p){ return *p; }
DEV float ldf(const u16* p){ return bf2f(*p); }

// ---------------------------------------------------------------------------
// Generic 64x64-tile transpose, any->bf16: dst[c][r] = src[r][c]
// grid: (R/64, C/64, batch), block 256
template<typename T>
__global__ __launch_bounds__(256) void tr_to_bf16(
    const T* __restrict__ src, u16* __restrict__ dst,
    int R, int C, long sB, long dB)
{
  __shared__ float tile[64][65];
  const int b = blockIdx.z;
  src += (long)b * sB;
  dst += (long)b * dB;
  const int r0 = blockIdx.x * 64, c0 = blockIdx.y * 64;
  const int t = threadIdx.x;
  const int rr = t >> 2, cc = (t & 3) * 16;
  const T* sp = src + (long)(r0 + rr) * C + (c0 + cc);
  #pragma unroll
  for (int q = 0; q < 16; q++) tile[rr][cc + q] = ldf(sp + q);
  __syncthreads();
  u16* dp = dst + (long)(c0 + rr) * R + (r0 + cc);
  #pragma unroll
  for (int q = 0; q < 16; q++) dp[q] = f2bf(tile[cc + q][rr]);
}

// ---------------------------------------------------------------------------
// NT GEMM tile core: C[i][j] = sum_k A[i][k] * B[j][k], A/B row-major bf16.
// Block = WR*WC waves; wave (wr,wc) owns (MF*16) x (NF*16) of the BM x BN tile.
// Staging: global_load_lds 16B, linear LDS (wave-uniform base + lane*16).
template<int BM, int BN, int BK, int WR, int WC, int MF, int NF>
DEV void gemm_nt(const u16* __restrict__ A, const u16* __restrict__ B,
                 int K, int arow0, int brow0,
                 f32x4 (&acc)[MF][NF], u16* As, u16* Bs)
{
  const int tid  = threadIdx.x;
  const int lane = tid & 63;
  const int w    = tid >> 6;
  const int wr   = w / WC, wc = w % WC;
  constexpr int NT   = WR * WC * 64;
  constexpr int AISS = (BM * BK * 2) / (NT * 16);
  constexpr int BISS = (BN * BK * 2) / (NT * 16);

  #pragma unroll
  for (int m = 0; m < MF; m++)
    #pragma unroll
    for (int n = 0; n < NF; n++) acc[m][n] = f32x4{0.f, 0.f, 0.f, 0.f};

  const int frow = lane & 15;          // fragment row (m / n index)
  const int fk   = (lane >> 4) * 8;    // fragment k offset

  for (int kt = 0; kt < K; kt += BK) {
    __syncthreads();   // previous iteration's LDS reads done
    #pragma unroll
    for (int q = 0; q < AISS; q++) {
      const int boff = q * NT * 16 + tid * 16;
      const int row  = boff / (BK * 2);
      const int kk   = (boff % (BK * 2)) >> 1;
      const u16* src = A + (long)(arow0 + row) * K + kt + kk;
      __builtin_amdgcn_global_load_lds(
          (const __attribute__((address_space(1))) void*)src,
          (__attribute__((address_space(3))) void*)(As + (boff >> 1)), 16, 0, 0);
    }
    #pragma unroll
    for (int q = 0; q < BISS; q++) {
      const int boff = q * NT * 16 + tid * 16;
      const int row  = boff / (BK * 2);
      const int kk   = (boff % (BK * 2)) >> 1;
      const u16* src = B + (long)(brow0 + row) * K + kt + kk;
      __builtin_amdgcn_global_load_lds(
          (const __attribute__((address_space(1))) void*)src,
          (__attribute__((address_space(3))) void*)(Bs + (boff >> 1)), 16, 0, 0);
    }
    asm volatile("s_waitcnt vmcnt(0)" ::: "memory");
    __syncthreads();
    #pragma unroll
    for (int ks = 0; ks < BK / 32; ++ks) {
      bf16x8 af[MF], bfr[NF];
      #pragma unroll
      for (int m = 0; m < MF; m++) {
        const int row = wr * (MF * 16) + m * 16 + frow;
        af[m] = *(const bf16x8*)(As + row * BK + ks * 32 + fk);
      }
      #pragma unroll
      for (int n = 0; n < NF; n++) {
        const int row = wc * (NF * 16) + n * 16 + frow;
        bfr[n] = *(const bf16x8*)(Bs + row * BK + ks * 32 + fk);
      }
      #pragma unroll
      for (int m = 0; m < MF; m++)
        #pragma unroll
        for (int n = 0; n < NF; n++)
          acc[m][n] = __builtin_amdgcn_mfma_f32_16x16x32_bf16(af[m], bfr[n], acc[m][n], 0, 0, 0);
    }
  }
}

// ---------------------------------------------------------------------------
// K1: proj = xt @ Wp^T + bias -> split into Q/K/V (bf16), layout [b][h][s][d]
__global__ __launch_bounds__(256) void k_proj(
    const u16* __restrict__ xt, const u16* __restrict__ Wtp,
    const float* __restrict__ bp,
    u16* __restrict__ Q, u16* __restrict__ Kb, u16* __restrict__ V)
{
  __shared__ __align__(16) u16 As[128 * 64];
  __shared__ __align__(16) u16 Bs[128 * 64];
  f32x4 acc[4][4];
  const int arow0 = blockIdx.x * 128, brow0 = blockIdx.y * 128;
  gemm_nt<128, 128, 64, 2, 2, 4, 4>(xt, Wtp, 64, arow0, brow0, acc, As, Bs);
  const int lane = threadIdx.x & 63;
  const int w = threadIdx.x >> 6;
  const int wr = w >> 1, wc = w & 1;
  const int gm0 = arow0 + wr * 64;
  const int gn0 = brow0 + wc * 64;
  #pragma unroll
  for (int m = 0; m < 4; m++)
    #pragma unroll
    for (int n = 0; n < 4; n++)
      #pragma unroll
      for (int j = 0; j < 4; j++) {
        const int gm = gm0 + m * 16 + (lane >> 4) * 4 + j;
        const int gn = gn0 + n * 16 + (lane & 15);
        const float v = acc[m][n][j] + bp[gn];
        const int b = gm >> 10, s = gm & 1023;
        const int h = gn / 1920, r = gn % 1920;
        const long base = ((long)(b * 4 + h) * 1024 + s) * 640;
        const u16 bv = f2bf(v);
        if (r < 640)       Q [base + r]        = bv;
        else if (r < 1280) Kb[base + r - 640]  = bv;
        else               V [base + r - 1280] = bv;
      }
}

// K2: S[b][h][i][j] = SCALE * sum_d Q[i,d] K[j,d]   (bf16 out)
__global__ __launch_bounds__(256) void k_qk(
    const u16* __restrict__ Q, const u16* __restrict__ Kb, u16* __restrict__ S)
{
  __shared__ __align__(16) u16 As[128 * 64];
  __shared__ __align__(16) u16 Bs[128 * 64];
  const int bh = blockIdx.z;
  f32x4 acc[4][4];
  gemm_nt<128, 128, 64, 2, 2, 4, 4>(Q + (long)bh * 655360, Kb + (long)bh * 655360, 640,
                                    blockIdx.x * 128, blockIdx.y * 128, acc, As, Bs);
  const int lane = threadIdx.x & 63;
  const int w = threadIdx.x >> 6;
  const int wr = w >> 1, wc = w & 1;
  u16* Sp = S + ((long)bh << 20);
  const int gi0 = blockIdx.x * 128 + wr * 64;
  const int gj0 = blockIdx.y * 128 + wc * 64;
  #pragma unroll
  for (int m = 0; m < 4; m++)
    #pragma unroll
    for (int n = 0; n < 4; n++)
      #pragma unroll
      for (int j = 0; j < 4; j++) {
        const int gi = gi0 + m * 16 + (lane >> 4) * 4 + j;
        const int gj = gj0 + n * 16 + (lane & 15);
        Sp[(long)gi * 1024 + gj] = f2bf(acc[m][n][j] * 0.03952847075210474f);
      }
}

// K3: fused column softmax over i (rows), in place.
// For each column j: M=max_i S[i][j], Z=sum_i exp(S-M); S[i][j] <- exp(S-M)/Z
// grid (16 col-chunks, 32 bh), block 256. Each block: [1024 rows][64 cols] slab.
__global__ __launch_bounds__(256) void k_stats_norm(u16* __restrict__ S)
{
  __shared__ float pm[32][64];
  __shared__ float pz[32][64];
  __shared__ float colM[64], colR[64];
  const int bh = blockIdx.y;
  const int c0 = blockIdx.x * 64;
  u16* Sp = S + ((long)bh << 20) + c0;
  const int t  = threadIdx.x;
  const int rg = t >> 3;          // 0..31 row-group
  const int cl = (t & 7) * 8;     // 0..56 col offset (8 cols per thread)
  float m[8], z[8];
  #pragma unroll
  for (int e = 0; e < 8; e++){ m[e] = -3.0e38f; z[e] = 0.f; }
  // online max+sum, one pass, bf16x8 coalesced loads
  for (int i = rg; i < 1024; i += 32) {
    bf16x8 v = *(const bf16x8*)(Sp + ((long)i << 10) + cl);
    #pragma unroll
    for (int e = 0; e < 8; e++) {
      const float f  = bf2f((u16)v[e]);
      const float nm = fmaxf(m[e], f);
      z[e] = z[e] * __expf(m[e] - nm) + __expf(f - nm);
      m[e] = nm;
    }
  }
  #pragma unroll
  for (int e = 0; e < 8; e++){ pm[rg][cl + e] = m[e]; pz[rg][cl + e] = z[e]; }
  __syncthreads();
  if (t < 64) {
    float M = -3.0e38f;
    #pragma unroll 8
    for (int k = 0; k < 32; k++) M = fmaxf(M, pm[k][t]);
    float Z = 0.f;
    #pragma unroll 8
    for (int k = 0; k < 32; k++) Z += pz[k][t] * __expf(pm[k][t] - M);
    colM[t] = M;
    colR[t] = 1.0f / Z;
  }
  __syncthreads();
  float cm[8], cr[8];
  #pragma unroll
  for (int e = 0; e < 8; e++){ cm[e] = colM[cl + e]; cr[e] = colR[cl + e]; }
  // normalize + write back (fused, replaces the old k_norm kernel)
  for (int i = rg; i < 1024; i += 32) {
    bf16x8 v = *(const bf16x8*)(Sp + ((long)i << 10) + cl);
    bf16x8 r;
    #pragma unroll
    for (int e = 0; e < 8; e++)
      r[e] = (short)f2bf(__expf(bf2f((u16)v[e]) - cm[e]) * cr[e]);
    *(bf16x8*)(Sp + ((long)i << 10) + cl) = r;
  }
}

// K5: att[b][s][h*640+d] = sum_j P[i][j] * Vt[d][j]
__global__ __launch_bounds__(256) void k_pv(
    const u16* __restrict__ P, const u16* __restrict__ Vt, u16* __restrict__ att)
{
  __shared__ __align__(16) u16 As[128 * 64];
  __shared__ __align__(16) u16 Bs[128 * 64];
  const int bh = blockIdx.z;
  f32x4 acc[4][4];
  gemm_nt<128, 128, 64, 2, 2, 4, 4>(P + ((long)bh << 20), Vt + (long)bh * 655360, 1024,
                                    blockIdx.x * 128, blockIdx.y * 128, acc, As, Bs);
  const int lane = threadIdx.x & 63;
  const int w = threadIdx.x >> 6;
  const int wr = w >> 1, wc = w & 1;
  const int b = bh >> 2, h = bh & 3;
  const int gi0 = blockIdx.x * 128 + wr * 64;
  const int gd0 = blockIdx.y * 128 + wc * 64;
  #pragma unroll
  for (int m = 0; m < 4; m++)
    #pragma unroll
    for (int n = 0; n < 4; n++)
      #pragma unroll
      for (int j = 0; j < 4; j++) {
        const int gi = gi0 + m * 16 + (lane >> 4) * 4 + j;
        const int gd = gd0 + n * 16 + (lane & 15);
        att[((long)b * 1024 + gi) * 2560 + h * 640 + gd] = f2bf(acc[m][n][j]);
      }
}

// K6: out[b][c][s] = att @ Wo^T + bo + x   (writes f32 output, fused residual)
__global__ __launch_bounds__(256) void k_out(
    const u16* __restrict__ att, const u16* __restrict__ Wot,
    const float* __restrict__ bo, const float* __restrict__ x, float* __restrict__ out)
{
  __shared__ __align__(16) u16 As[128 * 64];
  __shared__ __align__(16) u16 Bs[64 * 64];
  f32x4 acc[2][4];
  gemm_nt<128, 64, 64, 4, 1, 2, 4>(att, Wot, 2560, blockIdx.x * 128, 0, acc, As, Bs);
  const int lane = threadIdx.x & 63;
  const int wr = threadIdx.x >> 6;
  const int gm0 = blockIdx.x * 128 + wr * 32;
  #pragma unroll
  for (int m = 0; m < 2; m++)
    #pragma unroll
    for (int n = 0; n < 4; n++)
      #pragma unroll
      for (int j = 0; j < 4; j++) {
        const int gm = gm0 + m * 16 + (lane >> 4) * 4 + j;
        const int gn = n * 16 + (lane & 15);
        const int b = gm >> 10, s = gm & 1023;
        const long xi = ((long)b * 64 + gn) * 1024 + s;
        out[xi] = acc[m][n][j] + bo[gn] + x[xi];
      }
}

// ---------------------------------------------------------------------------
extern "C" void kernel_launch(void* const* d_in, const int* in_sizes, int n_in,
                              void* d_out, int out_size, void* d_ws, size_t ws_size,
                              hipStream_t stream)
{
  (void)in_sizes; (void)n_in; (void)out_size; (void)ws_size;
  const float* x  = (const float*)d_in[0];
  // d_in[1] = t (unused)
  const float* Wp = (const float*)d_in[2];
  const float* bp = (const float*)d_in[3];
  const float* Wo = (const float*)d_in[4];
  const float* bo = (const float*)d_in[5];
  float* out = (float*)d_out;

  char* w8 = (char*)d_ws;
  // byte offsets (196 MB total); att aliases Q, Vt aliases K (dead by then)
  u16* Q   = (u16*)(w8 + 0L);           // [32][1024][640] bf16, 40 MB
  u16* Kb  = (u16*)(w8 + 41943040L);    // 40 MB
  u16* V   = (u16*)(w8 + 83886080L);    // 40 MB
  u16* S   = (u16*)(w8 + 125829120L);   // [32][1024][1024] bf16, 64 MB
  u16* att = Q;                         // reuse Q space after k_qk
  u16* Vt  = Kb;                        // reuse K space after k_qk
  u16* xt  = (u16*)(w8 + 192937984L);   // [8192][64] bf16, 1 MB
  u16* Wtp = (u16*)(w8 + 193986560L);   // [7680][64] bf16
  u16* Wot = (u16*)(w8 + 194969600L);   // [64][2560] bf16

  // input transposes -> bf16 NT operands
  tr_to_bf16<float><<<dim3(1, 16, 8),  256, 0, stream>>>(x,  xt,  64, 1024, 65536L, 65536L);
  tr_to_bf16<float><<<dim3(1, 120, 1), 256, 0, stream>>>(Wp, Wtp, 64, 7680, 0L, 0L);
  tr_to_bf16<float><<<dim3(40, 1, 1),  256, 0, stream>>>(Wo, Wot, 2560, 64, 0L, 0L);
  // pipeline
  k_proj<<<dim3(64, 60),   256, 0, stream>>>(xt, Wtp, bp, Q, Kb, V);
  k_qk  <<<dim3(8, 8, 32), 256, 0, stream>>>(Q, Kb, S);
  tr_to_bf16<u16><<<dim3(16, 10, 32), 256, 0, stream>>>(V, Vt, 1024, 640, 655360L, 655360L);
  k_stats_norm<<<dim3(16, 32), 256, 0, stream>>>(S);
  k_pv  <<<dim3(8, 5, 32), 256, 0, stream>>>(S, Vt, att);
  k_out <<<64,             256, 0, stream>>>(att, Wot, bo, x, out);
}

// Round 3
// 265.996 us; speedup vs baseline: 1.8955x; 1.1215x over previous
//
#include <hip/hip_runtime.h>
#include <hip/hip_bf16.h>
#include <stdint.h>

typedef unsigned short u16;
typedef __attribute__((ext_vector_type(4))) float f32x4;
typedef __attribute__((ext_vector_type(8))) short bf16x8;

#define DEV __device__ __forceinline__

DEV float bf2f(u16 b){ unsigned u = ((unsigned)b) << 16; return __builtin_bit_cast(float, u); }
DEV u16 f2bf(float f){
  unsigned u = __builtin_bit_cast(unsigned, f);
  u += 0x7FFFu + ((u >> 16) & 1u);
  return (u16)(u >> 16);
}
DEV float ldf(const float* p){ return *p; }
DEV float ldf(const u16* p){ return bf2f(*p); }

// XCD-aware block swizzle (T1). Requires nwg % 8 == 0.
DEV int xcd_swz(int nwg){
  const int bid = (int)blockIdx.x;
  return (bid & 7) * (nwg >> 3) + (bid >> 3);
}

// ---------------------------------------------------------------------------
// Generic 64x64-tile transpose, any->bf16: dst[c][r] = src[r][c]
template<typename T>
__global__ __launch_bounds__(256) void tr_to_bf16(
    const T* __restrict__ src, u16* __restrict__ dst,
    int R, int C, long sB, long dB)
{
  __shared__ float tile[64][65];
  const int b = blockIdx.z;
  src += (long)b * sB;
  dst += (long)b * dB;
  const int r0 = blockIdx.x * 64, c0 = blockIdx.y * 64;
  const int t = threadIdx.x;
  const int rr = t >> 2, cc = (t & 3) * 16;
  const T* sp = src + (long)(r0 + rr) * C + (c0 + cc);
  #pragma unroll
  for (int q = 0; q < 16; q++) tile[rr][cc + q] = ldf(sp + q);
  __syncthreads();
  u16* dp = dst + (long)(c0 + rr) * R + (r0 + cc);
  #pragma unroll
  for (int q = 0; q < 16; q++) dp[q] = f2bf(tile[cc + q][rr]);
}

// ---------------------------------------------------------------------------
// NT GEMM tile core, 2-phase double-buffered (T3-minimum) + st-style XOR
// swizzle (T2, both-sides: pre-swizzled global source slot + swizzled ds_read).
// C[i][j] = sum_k A[i][k]*B[j][k]; A/B row-major bf16.
// As/Bs are 2*BM*BK / 2*BN*BK u16 (double buffers).
template<int BM, int BN, int BK, int WR, int WC, int MF, int NF>
DEV void gemm_nt(const u16* __restrict__ A, const u16* __restrict__ B,
                 int K, int arow0, int brow0,
                 f32x4 (&acc)[MF][NF], u16* As, u16* Bs)
{
  const int tid  = threadIdx.x;
  const int lane = tid & 63;
  const int w    = tid >> 6;
  const int wr   = w / WC, wc = w % WC;
  constexpr int NT   = WR * WC * 64;
  constexpr int AISS = (BM * BK * 2) / (NT * 16);
  constexpr int BISS = (BN * BK * 2) / (NT * 16);
  constexpr int ABUF = BM * BK;   // u16 per buffer
  constexpr int BBUF = BN * BK;

  #pragma unroll
  for (int m = 0; m < MF; m++)
    #pragma unroll
    for (int n = 0; n < NF; n++) acc[m][n] = f32x4{0.f, 0.f, 0.f, 0.f};

  const int frow = lane & 15;          // fragment row
  const int fs   = lane >> 4;          // fragment k slot sub-index (0..3)

  // stage one K-tile into buffer `buf`; linear LDS dest, source slot XOR'd
  auto stage = [&](int buf, int kt) {
    #pragma unroll
    for (int q = 0; q < AISS; q++) {
      const int boff = q * NT * 16 + tid * 16;       // byte offset in tile
      const int row  = boff / (BK * 2);
      const int slot = (boff % (BK * 2)) >> 4;       // 16B slot in row
      const int kk   = ((slot ^ (row & 7)) << 3);    // swizzled source k
      const u16* src = A + (long)(arow0 + row) * K + kt + kk;
      __builtin_amdgcn_global_load_lds(
          (const __attribute__((address_space(1))) void*)src,
          (__attribute__((address_space(3))) void*)(As + buf * ABUF + (boff >> 1)), 16, 0, 0);
    }
    #pragma unroll
    for (int q = 0; q < BISS; q++) {
      const int boff = q * NT * 16 + tid * 16;
      const int row  = boff / (BK * 2);
      const int slot = (boff % (BK * 2)) >> 4;
      const int kk   = ((slot ^ (row & 7)) << 3);
      const u16* src = B + (long)(brow0 + row) * K + kt + kk;
      __builtin_amdgcn_global_load_lds(
          (const __attribute__((address_space(1))) void*)src,
          (__attribute__((address_space(3))) void*)(Bs + buf * BBUF + (boff >> 1)), 16, 0, 0);
    }
  };

  auto compute = [&](int buf) {
    __builtin_amdgcn_s_setprio(1);
    #pragma unroll
    for (int ks = 0; ks < BK / 32; ++ks) {
      bf16x8 af[MF], bfr[NF];
      #pragma unroll
      for (int m = 0; m < MF; m++) {
        const int row  = wr * (MF * 16) + m * 16 + frow;
        const int slot = (ks * 4 + fs) ^ (row & 7);
        af[m] = *(const bf16x8*)(As + buf * ABUF + row * BK + slot * 8);
      }
      #pragma unroll
      for (int n = 0; n < NF; n++) {
        const int row  = wc * (NF * 16) + n * 16 + frow;
        const int slot = (ks * 4 + fs) ^ (row & 7);
        bfr[n] = *(const bf16x8*)(Bs + buf * BBUF + row * BK + slot * 8);
      }
      #pragma unroll
      for (int m = 0; m < MF; m++)
        #pragma unroll
        for (int n = 0; n < NF; n++)
          acc[m][n] = __builtin_amdgcn_mfma_f32_16x16x32_bf16(af[m], bfr[n], acc[m][n], 0, 0, 0);
    }
    __builtin_amdgcn_s_setprio(0);
  };

  // prologue
  stage(0, 0);
  asm volatile("s_waitcnt vmcnt(0)" ::: "memory");
  __syncthreads();
  int cur = 0;
  // steady state: prefetch t+1 while computing t
  for (int kt = BK; kt < K; kt += BK) {
    stage(cur ^ 1, kt);
    compute(cur);
    asm volatile("s_waitcnt vmcnt(0)" ::: "memory");
    __syncthreads();
    cur ^= 1;
  }
  compute(cur);   // last tile
}

// ---------------------------------------------------------------------------
// K1: proj = xt @ Wp^T + bias -> split into Q/K/V (bf16), layout [b][h][s][d]
__global__ __launch_bounds__(256) void k_proj(
    const u16* __restrict__ xt, const u16* __restrict__ Wtp,
    const float* __restrict__ bp,
    u16* __restrict__ Q, u16* __restrict__ Kb, u16* __restrict__ V)
{
  __shared__ __align__(16) u16 As[2 * 128 * 64];
  __shared__ __align__(16) u16 Bs[2 * 128 * 64];
  f32x4 acc[4][4];
  const int arow0 = blockIdx.x * 128, brow0 = blockIdx.y * 128;
  gemm_nt<128, 128, 64, 2, 2, 4, 4>(xt, Wtp, 64, arow0, brow0, acc, As, Bs);
  const int lane = threadIdx.x & 63;
  const int w = threadIdx.x >> 6;
  const int wr = w >> 1, wc = w & 1;
  const int gm0 = arow0 + wr * 64;
  const int gn0 = brow0 + wc * 64;
  #pragma unroll
  for (int m = 0; m < 4; m++)
    #pragma unroll
    for (int n = 0; n < 4; n++)
      #pragma unroll
      for (int j = 0; j < 4; j++) {
        const int gm = gm0 + m * 16 + (lane >> 4) * 4 + j;
        const int gn = gn0 + n * 16 + (lane & 15);
        const float v = acc[m][n][j] + bp[gn];
        const int b = gm >> 10, s = gm & 1023;
        const int h = gn / 1920, r = gn % 1920;
        const long base = ((long)(b * 4 + h) * 1024 + s) * 640;
        const u16 bv = f2bf(v);
        if (r < 640)       Q [base + r]        = bv;
        else if (r < 1280) Kb[base + r - 640]  = bv;
        else               V [base + r - 1280] = bv;
      }
}

// K2: S[b][h][i][j] = SCALE * sum_d Q[i,d] K[j,d]   (bf16 out), 1-D swizzled grid
__global__ __launch_bounds__(256) void k_qk(
    const u16* __restrict__ Q, const u16* __restrict__ Kb, u16* __restrict__ S)
{
  __shared__ __align__(16) u16 As[2 * 128 * 64];
  __shared__ __align__(16) u16 Bs[2 * 128 * 64];
  const int id = xcd_swz(2048);
  const int bh = id >> 6;
  const int ti = id & 7;
  const int tj = (id & 63) >> 3;
  f32x4 acc[4][4];
  gemm_nt<128, 128, 64, 2, 2, 4, 4>(Q + (long)bh * 655360, Kb + (long)bh * 655360, 640,
                                    ti * 128, tj * 128, acc, As, Bs);
  const int lane = threadIdx.x & 63;
  const int w = threadIdx.x >> 6;
  const int wr = w >> 1, wc = w & 1;
  u16* Sp = S + ((long)bh << 20);
  const int gi0 = ti * 128 + wr * 64;
  const int gj0 = tj * 128 + wc * 64;
  #pragma unroll
  for (int m = 0; m < 4; m++)
    #pragma unroll
    for (int n = 0; n < 4; n++)
      #pragma unroll
      for (int j = 0; j < 4; j++) {
        const int gi = gi0 + m * 16 + (lane >> 4) * 4 + j;
        const int gj = gj0 + n * 16 + (lane & 15);
        Sp[(long)gi * 1024 + gj] = f2bf(acc[m][n][j] * 0.03952847075210474f);
      }
}

// K3: fused column softmax over i (rows), in place.
__global__ __launch_bounds__(256) void k_stats_norm(u16* __restrict__ S)
{
  __shared__ float pm[32][64];
  __shared__ float pz[32][64];
  __shared__ float colM[64], colR[64];
  const int bh = blockIdx.y;
  const int c0 = blockIdx.x * 64;
  u16* Sp = S + ((long)bh << 20) + c0;
  const int t  = threadIdx.x;
  const int rg = t >> 3;          // 0..31 row-group
  const int cl = (t & 7) * 8;     // 0..56 col offset
  float m[8], z[8];
  #pragma unroll
  for (int e = 0; e < 8; e++){ m[e] = -3.0e38f; z[e] = 0.f; }
  for (int i = rg; i < 1024; i += 32) {
    bf16x8 v = *(const bf16x8*)(Sp + ((long)i << 10) + cl);
    #pragma unroll
    for (int e = 0; e < 8; e++) {
      const float f  = bf2f((u16)v[e]);
      const float nm = fmaxf(m[e], f);
      z[e] = z[e] * __expf(m[e] - nm) + __expf(f - nm);
      m[e] = nm;
    }
  }
  #pragma unroll
  for (int e = 0; e < 8; e++){ pm[rg][cl + e] = m[e]; pz[rg][cl + e] = z[e]; }
  __syncthreads();
  if (t < 64) {
    float M = -3.0e38f;
    #pragma unroll 8
    for (int k = 0; k < 32; k++) M = fmaxf(M, pm[k][t]);
    float Z = 0.f;
    #pragma unroll 8
    for (int k = 0; k < 32; k++) Z += pz[k][t] * __expf(pm[k][t] - M);
    colM[t] = M;
    colR[t] = 1.0f / Z;
  }
  __syncthreads();
  float cm[8], cr[8];
  #pragma unroll
  for (int e = 0; e < 8; e++){ cm[e] = colM[cl + e]; cr[e] = colR[cl + e]; }
  for (int i = rg; i < 1024; i += 32) {
    bf16x8 v = *(const bf16x8*)(Sp + ((long)i << 10) + cl);
    bf16x8 r;
    #pragma unroll
    for (int e = 0; e < 8; e++)
      r[e] = (short)f2bf(__expf(bf2f((u16)v[e]) - cm[e]) * cr[e]);
    *(bf16x8*)(Sp + ((long)i << 10) + cl) = r;
  }
}

// K5: att[b][s][h*640+d] = sum_j P[i][j] * Vt[d][j], 1-D swizzled grid
__global__ __launch_bounds__(256) void k_pv(
    const u16* __restrict__ P, const u16* __restrict__ Vt, u16* __restrict__ att)
{
  __shared__ __align__(16) u16 As[2 * 128 * 64];
  __shared__ __align__(16) u16 Bs[2 * 128 * 64];
  const int id = xcd_swz(1280);
  const int bh = id / 40;
  const int rem = id - bh * 40;
  const int ti = rem & 7;
  const int td = rem >> 3;       // 0..4
  f32x4 acc[4][4];
  gemm_nt<128, 128, 64, 2, 2, 4, 4>(P + ((long)bh << 20), Vt + (long)bh * 655360, 1024,
                                    ti * 128, td * 128, acc, As, Bs);
  const int lane = threadIdx.x & 63;
  const int w = threadIdx.x >> 6;
  const int wr = w >> 1, wc = w & 1;
  const int b = bh >> 2, h = bh & 3;
  const int gi0 = ti * 128 + wr * 64;
  const int gd0 = td * 128 + wc * 64;
  #pragma unroll
  for (int m = 0; m < 4; m++)
    #pragma unroll
    for (int n = 0; n < 4; n++)
      #pragma unroll
      for (int j = 0; j < 4; j++) {
        const int gi = gi0 + m * 16 + (lane >> 4) * 4 + j;
        const int gd = gd0 + n * 16 + (lane & 15);
        att[((long)b * 1024 + gi) * 2560 + h * 640 + gd] = f2bf(acc[m][n][j]);
      }
}

// K6: out[b][c][s] = att @ Wo^T + bo + x   (f32 out, fused residual)
__global__ __launch_bounds__(256) void k_out(
    const u16* __restrict__ att, const u16* __restrict__ Wot,
    const float* __restrict__ bo, const float* __restrict__ x, float* __restrict__ out)
{
  __shared__ __align__(16) u16 As[2 * 128 * 64];
  __shared__ __align__(16) u16 Bs[2 * 64 * 64];
  f32x4 acc[2][4];
  gemm_nt<128, 64, 64, 4, 1, 2, 4>(att, Wot, 2560, blockIdx.x * 128, 0, acc, As, Bs);
  const int lane = threadIdx.x & 63;
  const int wr = threadIdx.x >> 6;
  const int gm0 = blockIdx.x * 128 + wr * 32;
  #pragma unroll
  for (int m = 0; m < 2; m++)
    #pragma unroll
    for (int n = 0; n < 4; n++)
      #pragma unroll
      for (int j = 0; j < 4; j++) {
        const int gm = gm0 + m * 16 + (lane >> 4) * 4 + j;
        const int gn = n * 16 + (lane & 15);
        const int b = gm >> 10, s = gm & 1023;
        const long xi = ((long)b * 64 + gn) * 1024 + s;
        out[xi] = acc[m][n][j] + bo[gn] + x[xi];
      }
}

// ---------------------------------------------------------------------------
extern "C" void kernel_launch(void* const* d_in, const int* in_sizes, int n_in,
                              void* d_out, int out_size, void* d_ws, size_t ws_size,
                              hipStream_t stream)
{
  (void)in_sizes; (void)n_in; (void)out_size; (void)ws_size;
  const float* x  = (const float*)d_in[0];
  // d_in[1] = t (unused)
  const float* Wp = (const float*)d_in[2];
  const float* bp = (const float*)d_in[3];
  const float* Wo = (const float*)d_in[4];
  const float* bo = (const float*)d_in[5];
  float* out = (float*)d_out;

  char* w8 = (char*)d_ws;
  u16* Q   = (u16*)(w8 + 0L);           // [32][1024][640] bf16, 40 MB
  u16* Kb  = (u16*)(w8 + 41943040L);    // 40 MB
  u16* V   = (u16*)(w8 + 83886080L);    // 40 MB
  u16* S   = (u16*)(w8 + 125829120L);   // [32][1024][1024] bf16, 64 MB
  u16* att = Q;                         // reuse Q space after k_qk
  u16* Vt  = Kb;                        // reuse K space after k_qk
  u16* xt  = (u16*)(w8 + 192937984L);   // [8192][64] bf16
  u16* Wtp = (u16*)(w8 + 193986560L);   // [7680][64] bf16
  u16* Wot = (u16*)(w8 + 194969600L);   // [64][2560] bf16

  tr_to_bf16<float><<<dim3(1, 16, 8),  256, 0, stream>>>(x,  xt,  64, 1024, 65536L, 65536L);
  tr_to_bf16<float><<<dim3(1, 120, 1), 256, 0, stream>>>(Wp, Wtp, 64, 7680, 0L, 0L);
  tr_to_bf16<float><<<dim3(40, 1, 1),  256, 0, stream>>>(Wo, Wot, 2560, 64, 0L, 0L);
  k_proj<<<dim3(64, 60),   256, 0, stream>>>(xt, Wtp, bp, Q, Kb, V);
  k_qk  <<<2048,           256, 0, stream>>>(Q, Kb, S);
  tr_to_bf16<u16><<<dim3(16, 10, 32), 256, 0, stream>>>(V, Vt, 1024, 640, 655360L, 655360L);
  k_stats_norm<<<dim3(16, 32), 256, 0, stream>>>(S);
  k_pv  <<<1280,           256, 0, stream>>>(S, Vt, att);
  k_out <<<64,             256, 0, stream>>>(att, Wot, bo, x, out);
}

// Round 4
// 235.312 us; speedup vs baseline: 2.1427x; 1.1304x over previous
//
#include <hip/hip_runtime.h>
#include <hip/hip_bf16.h>
#include <stdint.h>

typedef unsigned short u16;
typedef __attribute__((ext_vector_type(4))) float f32x4;
typedef __attribute__((ext_vector_type(8))) short bf16x8;

#define DEV __device__ __forceinline__

DEV float bf2f(u16 b){ unsigned u = ((unsigned)b) << 16; return __builtin_bit_cast(float, u); }
DEV u16 f2bf(float f){
  unsigned u = __builtin_bit_cast(unsigned, f);
  u += 0x7FFFu + ((u >> 16) & 1u);
  return (u16)(u >> 16);
}
DEV float ldf(const float* p){ return *p; }
DEV float ldf(const u16* p){ return bf2f(*p); }

// XCD-aware block swizzle (T1). Requires nwg % 8 == 0.
DEV int xcd_swz(int nwg){
  const int bid = (int)blockIdx.x;
  return (bid & 7) * (nwg >> 3) + (bid >> 3);
}

// ---------------------------------------------------------------------------
// f32 -> bf16 flat cast, 8 elems/thread
__global__ __launch_bounds__(256) void k_cast(
    const float* __restrict__ s, u16* __restrict__ d, int nchunks)
{
  const int i = blockIdx.x * 256 + threadIdx.x;
  if (i >= nchunks) return;
  const f32x4 a = *(const f32x4*)(s + (long)i * 8);
  const f32x4 b = *(const f32x4*)(s + (long)i * 8 + 4);
  bf16x8 r;
  #pragma unroll
  for (int e = 0; e < 4; e++){ r[e] = (short)f2bf(a[e]); r[e+4] = (short)f2bf(b[e]); }
  *(bf16x8*)(d + (long)i * 8) = r;
}

// Generic 64x64-tile transpose, any->bf16: dst[c][r] = src[r][c]
template<typename T>
__global__ __launch_bounds__(256) void tr_to_bf16(
    const T* __restrict__ src, u16* __restrict__ dst,
    int R, int C, long sB, long dB)
{
  __shared__ float tile[64][65];
  const int b = blockIdx.z;
  src += (long)b * sB;
  dst += (long)b * dB;
  const int r0 = blockIdx.x * 64, c0 = blockIdx.y * 64;
  const int t = threadIdx.x;
  const int rr = t >> 2, cc = (t & 3) * 16;
  const T* sp = src + (long)(r0 + rr) * C + (c0 + cc);
  #pragma unroll
  for (int q = 0; q < 16; q++) tile[rr][cc + q] = ldf(sp + q);
  __syncthreads();
  u16* dp = dst + (long)(c0 + rr) * R + (r0 + cc);
  #pragma unroll
  for (int q = 0; q < 16; q++) dp[q] = f2bf(tile[cc + q][rr]);
}

// ---------------------------------------------------------------------------
// NT GEMM tile core, 2-phase double-buffered + both-sides XOR swizzle.
// C[i][j] = sum_k A[i][k]*B[j][k]; A/B row-major bf16 with leading dims lda/ldb.
template<int BM, int BN, int BK, int WR, int WC, int MF, int NF>
DEV void gemm_nt(const u16* __restrict__ A, const u16* __restrict__ B,
                 int K, long lda, long ldb, int arow0, int brow0,
                 f32x4 (&acc)[MF][NF], u16* As, u16* Bs)
{
  const int tid  = threadIdx.x;
  const int lane = tid & 63;
  const int w    = tid >> 6;
  const int wr   = w / WC, wc = w % WC;
  constexpr int NT   = WR * WC * 64;
  constexpr int AISS = (BM * BK * 2) / (NT * 16);
  constexpr int BISS = (BN * BK * 2) / (NT * 16);
  constexpr int ABUF = BM * BK;
  constexpr int BBUF = BN * BK;

  #pragma unroll
  for (int m = 0; m < MF; m++)
    #pragma unroll
    for (int n = 0; n < NF; n++) acc[m][n] = f32x4{0.f, 0.f, 0.f, 0.f};

  const int frow = lane & 15;
  const int fs   = lane >> 4;

  auto stage = [&](int buf, int kt) {
    #pragma unroll
    for (int q = 0; q < AISS; q++) {
      const int boff = q * NT * 16 + tid * 16;
      const int row  = boff / (BK * 2);
      const int slot = (boff % (BK * 2)) >> 4;
      const int kk   = ((slot ^ (row & 7)) << 3);
      const u16* src = A + (long)(arow0 + row) * lda + kt + kk;
      __builtin_amdgcn_global_load_lds(
          (const __attribute__((address_space(1))) void*)src,
          (__attribute__((address_space(3))) void*)(As + buf * ABUF + (boff >> 1)), 16, 0, 0);
    }
    #pragma unroll
    for (int q = 0; q < BISS; q++) {
      const int boff = q * NT * 16 + tid * 16;
      const int row  = boff / (BK * 2);
      const int slot = (boff % (BK * 2)) >> 4;
      const int kk   = ((slot ^ (row & 7)) << 3);
      const u16* src = B + (long)(brow0 + row) * ldb + kt + kk;
      __builtin_amdgcn_global_load_lds(
          (const __attribute__((address_space(1))) void*)src,
          (__attribute__((address_space(3))) void*)(Bs + buf * BBUF + (boff >> 1)), 16, 0, 0);
    }
  };

  auto compute = [&](int buf) {
    __builtin_amdgcn_s_setprio(1);
    #pragma unroll
    for (int ks = 0; ks < BK / 32; ++ks) {
      bf16x8 af[MF], bfr[NF];
      #pragma unroll
      for (int m = 0; m < MF; m++) {
        const int row  = wr * (MF * 16) + m * 16 + frow;
        const int slot = (ks * 4 + fs) ^ (row & 7);
        af[m] = *(const bf16x8*)(As + buf * ABUF + row * BK + slot * 8);
      }
      #pragma unroll
      for (int n = 0; n < NF; n++) {
        const int row  = wc * (NF * 16) + n * 16 + frow;
        const int slot = (ks * 4 + fs) ^ (row & 7);
        bfr[n] = *(const bf16x8*)(Bs + buf * BBUF + row * BK + slot * 8);
      }
      #pragma unroll
      for (int m = 0; m < MF; m++)
        #pragma unroll
        for (int n = 0; n < NF; n++)
          acc[m][n] = __builtin_amdgcn_mfma_f32_16x16x32_bf16(af[m], bfr[n], acc[m][n], 0, 0, 0);
    }
    __builtin_amdgcn_s_setprio(0);
  };

  stage(0, 0);
  asm volatile("s_waitcnt vmcnt(0)" ::: "memory");
  __syncthreads();
  int cur = 0;
  for (int kt = BK; kt < K; kt += BK) {
    stage(cur ^ 1, kt);
    compute(cur);
    asm volatile("s_waitcnt vmcnt(0)" ::: "memory");
    __syncthreads();
    cur ^= 1;
  }
  compute(cur);
}

// ---------------------------------------------------------------------------
// Per-wave epilogue: stage wave tile (MF*16 x NF*16) bf16 into LDS (chunk-XOR
// swizzled), then coalesced bf16x8 stores via fstore(row, col0, v).
// SH must hold WR*WC * MF*16 * NF*16 u16 (reuses dead As).
template<int MF, int NF, typename FV, typename FS>
DEV void epi_u16(u16* SH, FV&& fval, FS&& fstore)
{
  constexpr int RC = MF * 16, CC = NF * 16, CPR = NF * 2;
  const int lane = threadIdx.x & 63;
  const int w = threadIdx.x >> 6;
  u16* et = SH + w * (RC * CC);
  __syncthreads();                 // all waves done reading As/Bs
  #pragma unroll
  for (int m = 0; m < MF; m++)
    #pragma unroll
    for (int n = 0; n < NF; n++)
      #pragma unroll
      for (int j = 0; j < 4; j++) {
        const int row = m * 16 + (lane >> 4) * 4 + j;
        const int col = n * 16 + (lane & 15);
        et[row * CC + (((col >> 3) ^ row) & (CPR - 1)) * 8 + (col & 7)] =
            f2bf(fval(m, n, j, row, col));
      }
  constexpr int RPI = 64 / CPR;
  #pragma unroll
  for (int it = 0; it < RC / RPI; ++it) {
    const int row = it * RPI + lane / CPR;
    const int ch  = lane % CPR;
    bf16x8 v = *(const bf16x8*)(et + row * CC + ((ch ^ row) & (CPR - 1)) * 8);
    fstore(row, ch * 8, v);
  }
}

// ---------------------------------------------------------------------------
// Ahat[h][e][c] = sum_d Wp[e][kb+d] * Wp[c][qb+d]   (= (Wq Wk^T)^T entry)
__global__ __launch_bounds__(256) void k_prep(
    const u16* __restrict__ Wpb, u16* __restrict__ Ahat)
{
  __shared__ __align__(16) u16 SH[4 * 64 * 64];
  u16* As = SH; u16* Bs = SH + 2 * 64 * 64;
  const int h = blockIdx.x;
  f32x4 acc[2][2];
  gemm_nt<64, 64, 64, 2, 2, 2, 2>(Wpb + h * 1920 + 640, Wpb + h * 1920, 640,
                                  7680, 7680, 0, 0, acc, As, Bs);
  const int w = threadIdx.x >> 6;
  const int wr = w >> 1, wc = w & 1;
  u16* dst = Ahat + h * 4096;
  epi_u16<2, 2>(SH,
    [&](int m, int n, int j, int row, int col){ return acc[m][n][j]; },
    [&](int row, int c0, bf16x8 v){
      *(bf16x8*)(dst + (wr * 32 + row) * 64 + wc * 32 + c0) = v; });
}

// u_h[c] = Wq[c]·bk ; w_h[c] = bq·Wk[c] ; ch[h] = bq·bk
__global__ __launch_bounds__(256) void k_prepv(
    const float* __restrict__ Wp, const float* __restrict__ bp,
    float* __restrict__ uh, float* __restrict__ wh, float* __restrict__ ch)
{
  const int t = threadIdx.x, h = t >> 6, c = t & 63;
  const int qb = h * 1920, kb = qb + 640;
  float su = 0.f, sw = 0.f, sc = 0.f;
  for (int d = 0; d < 640; ++d) {
    const float bq = bp[qb + d], bk = bp[kb + d];
    su += Wp[(long)c * 7680 + qb + d] * bk;
    sw += bq * Wp[(long)c * 7680 + kb + d];
    sc += bq * bk;
  }
  uh[h * 64 + c] = su;
  wh[h * 64 + c] = sw;
  if (c == 0) ch[h] = sc;
}

// T[bh][i][e] = sum_c xt[b*1024+i][c] * Ahat[h][e][c]
__global__ __launch_bounds__(256) void k_T(
    const u16* __restrict__ xt, const u16* __restrict__ Ahat, u16* __restrict__ T)
{
  __shared__ __align__(16) u16 SH[2 * 128 * 64 + 2 * 64 * 64];
  u16* As = SH; u16* Bs = SH + 2 * 128 * 64;
  const int ti = blockIdx.x, bh = blockIdx.y;
  const int b = bh >> 2, h = bh & 3;
  f32x4 acc[2][4];
  gemm_nt<128, 64, 64, 4, 1, 2, 4>(xt, Ahat + h * 4096, 64, 64, 64,
                                   b * 1024 + ti * 128, 0, acc, As, Bs);
  const int wr = threadIdx.x >> 6;
  u16* dst = T + ((long)bh * 1024 + ti * 128 + wr * 32) * 64;
  epi_u16<2, 4>(SH,
    [&](int m, int n, int j, int row, int col){ return acc[m][n][j]; },
    [&](int row, int c0, bf16x8 v){ *(bf16x8*)(dst + (long)row * 64 + c0) = v; });
}

// ut[bh][i] = xt_row · u_h + ch[h] ; wt[bh][i] = xt_row · w_h
__global__ __launch_bounds__(256) void k_vecs(
    const u16* __restrict__ xt, const float* __restrict__ uh,
    const float* __restrict__ wh, const float* __restrict__ ch,
    float* __restrict__ ut, float* __restrict__ wt)
{
  const int idx = blockIdx.x * 256 + threadIdx.x;  // 32768
  const int bh = idx >> 10, i = idx & 1023;
  const int b = bh >> 2, h = bh & 3;
  const u16* xr = xt + ((long)b * 1024 + i) * 64;
  const float* u = uh + h * 64;
  const float* w = wh + h * 64;
  float su = 0.f, sw = 0.f;
  #pragma unroll
  for (int c8 = 0; c8 < 8; ++c8) {
    bf16x8 v = *(const bf16x8*)(xr + c8 * 8);
    #pragma unroll
    for (int e = 0; e < 8; e++) {
      const float f = bf2f((u16)v[e]);
      su += f * u[c8 * 8 + e];
      sw += f * w[c8 * 8 + e];
    }
  }
  ut[idx] = su + ch[h];
  wt[idx] = sw;
}

// P[bh][i][j] = exp(SCALE * (T_i · x_j + ut[i] + wt[j]))   (unnormalized)
__global__ __launch_bounds__(256) void k_qk(
    const u16* __restrict__ T, const u16* __restrict__ xt,
    const float* __restrict__ ut, const float* __restrict__ wt, u16* __restrict__ P)
{
  __shared__ __align__(16) u16 SH[4 * 128 * 64];
  u16* As = SH; u16* Bs = SH + 2 * 128 * 64;
  const int id = xcd_swz(2048);
  const int bh = id >> 6, ti = (id & 63) >> 3, tj = id & 7;
  const int b = bh >> 2;
  f32x4 acc[4][4];
  gemm_nt<128, 128, 64, 2, 2, 4, 4>(T + (long)bh * 65536, xt, 64, 64, 64,
                                    ti * 128, b * 1024 + tj * 128, acc, As, Bs);
  const int lane = threadIdx.x & 63;
  const int w = threadIdx.x >> 6;
  const int wr = w >> 1, wc = w & 1;
  const int gi0 = ti * 128 + wr * 64, gj0 = tj * 128 + wc * 64;
  const float* utp = ut + (bh << 10);
  const float* wtp = wt + (bh << 10);
  float rv[4][4], cv[4];
  #pragma unroll
  for (int m = 0; m < 4; m++)
    #pragma unroll
    for (int j = 0; j < 4; j++) rv[m][j] = utp[gi0 + m * 16 + (lane >> 4) * 4 + j];
  #pragma unroll
  for (int n = 0; n < 4; n++) cv[n] = wtp[gj0 + n * 16 + (lane & 15)];
  u16* dst = P + ((long)bh << 20);
  epi_u16<4, 4>(SH,
    [&](int m, int n, int j, int row, int col){
      return __expf((acc[m][n][j] + rv[m][j] + cv[n]) * 0.03952847075210474f);
    },
    [&](int row, int c0, bf16x8 v){
      *(bf16x8*)(dst + (long)(gi0 + row) * 1024 + gj0 + c0) = v; });
}

// V projection, written directly transposed: Vt[bh][d][s] (bf16, +bias)
__global__ __launch_bounds__(256) void k_projv(
    const u16* __restrict__ xt, const u16* __restrict__ Wtp,
    const float* __restrict__ bp, u16* __restrict__ Vt)
{
  __shared__ __align__(16) u16 SH[4 * 128 * 64];
  u16* As = SH; u16* Bs = SH + 2 * 128 * 64;
  const int bx = blockIdx.x, by = blockIdx.y;
  const int h = by / 5, d0 = (by % 5) * 128;
  const int vb = h * 1920 + 1280 + d0;
  f32x4 acc[4][4];
  gemm_nt<128, 128, 64, 2, 2, 4, 4>(xt, Wtp, 64, 64, 64, bx * 128, vb, acc, As, Bs);
  const int lane = threadIdx.x & 63;
  const int w = threadIdx.x >> 6;
  const int wr = w >> 1, wc = w & 1;
  const int b = bx >> 3, s0 = (bx & 7) * 128;
  float bv[4];
  #pragma unroll
  for (int n = 0; n < 4; n++) bv[n] = bp[vb + wc * 64 + n * 16 + (lane & 15)];
  u16* etb = SH;   // 128 x 128 u16 = 32 KB, block-wide transposed tile
  __syncthreads();
  #pragma unroll
  for (int m = 0; m < 4; m++)
    #pragma unroll
    for (int n = 0; n < 4; n++)
      #pragma unroll
      for (int j = 0; j < 4; j++) {
        const int sl = wr * 64 + m * 16 + (lane >> 4) * 4 + j;  // s_local
        const int dl = wc * 64 + n * 16 + (lane & 15);          // d_local
        etb[dl * 128 + (((sl >> 3) ^ dl) & 15) * 8 + (sl & 7)] = f2bf(acc[m][n][j] + bv[n]);
      }
  __syncthreads();
  const long base = ((long)(b * 4 + h) * 640 + d0) * 1024 + s0;
  #pragma unroll
  for (int it = 0; it < 8; ++it) {
    const int task = it * 256 + threadIdx.x;
    const int d = task >> 4, chk = task & 15;
    bf16x8 v = *(const bf16x8*)(etb + d * 128 + ((chk ^ d) & 15) * 8);
    *(bf16x8*)(Vt + base + (long)d * 1024 + chk * 8) = v;
  }
}

// Z[j] = sum_i P[i][j]; then Vt[bh][*][j] *= 1/Z[j]  (fused, in place)
__global__ __launch_bounds__(256) void k_colsum_vscale(
    const u16* __restrict__ P, u16* __restrict__ Vt)
{
  __shared__ float pz[16][128];
  __shared__ float Wl[128];
  const int jb = blockIdx.x, bh = blockIdx.y;
  const int t = threadIdx.x, jc = t & 15, rg = t >> 4;
  const u16* Pp = P + ((long)bh << 20) + jb * 128 + jc * 8;
  float z[8];
  #pragma unroll
  for (int e = 0; e < 8; e++) z[e] = 0.f;
  for (int i = rg; i < 1024; i += 16) {
    bf16x8 v = *(const bf16x8*)(Pp + ((long)i << 10));
    #pragma unroll
    for (int e = 0; e < 8; e++) z[e] += bf2f((u16)v[e]);
  }
  #pragma unroll
  for (int e = 0; e < 8; e++) pz[rg][jc * 8 + e] = z[e];
  __syncthreads();
  if (t < 128) {
    float Z = 0.f;
    #pragma unroll
    for (int k = 0; k < 16; k++) Z += pz[k][t];
    Wl[t] = 1.0f / Z;
  }
  __syncthreads();
  float wv[8];
  #pragma unroll
  for (int e = 0; e < 8; e++) wv[e] = Wl[jc * 8 + e];
  u16* Vp = Vt + (long)bh * 655360 + jb * 128 + jc * 8;
  for (int d = rg; d < 640; d += 16) {
    bf16x8 v = *(const bf16x8*)(Vp + (long)d * 1024);
    bf16x8 r;
    #pragma unroll
    for (int e = 0; e < 8; e++) r[e] = (short)f2bf(bf2f((u16)v[e]) * wv[e]);
    *(bf16x8*)(Vp + (long)d * 1024) = r;
  }
}

// att[b][s][h*640+d] = sum_j P[i][j] * Vt[d][j]   (Vt pre-scaled by 1/Z)
__global__ __launch_bounds__(256) void k_pv(
    const u16* __restrict__ P, const u16* __restrict__ Vt, u16* __restrict__ att)
{
  __shared__ __align__(16) u16 SH[4 * 128 * 64];
  u16* As = SH; u16* Bs = SH + 2 * 128 * 64;
  const int id = xcd_swz(1280);
  const int bh = id / 40;
  const int rem = id - bh * 40;
  const int ti = rem & 7, td = rem >> 3;
  f32x4 acc[4][4];
  gemm_nt<128, 128, 64, 2, 2, 4, 4>(P + ((long)bh << 20), Vt + (long)bh * 655360, 1024,
                                    1024, 1024, ti * 128, td * 128, acc, As, Bs);
  const int w = threadIdx.x >> 6;
  const int wr = w >> 1, wc = w & 1;
  const int b = bh >> 2, h = bh & 3;
  const int gi0 = ti * 128 + wr * 64, gd0 = td * 128 + wc * 64;
  epi_u16<4, 4>(SH,
    [&](int m, int n, int j, int row, int col){ return acc[m][n][j]; },
    [&](int row, int c0, bf16x8 v){
      *(bf16x8*)(att + ((long)(b << 10) + gi0 + row) * 2560 + h * 640 + gd0 + c0) = v; });
}

// out[b][c][s] = att @ Wo^T + bo + x   (f32, fused residual, coalesced stores)
__global__ __launch_bounds__(256) void k_out(
    const u16* __restrict__ att, const u16* __restrict__ Wot,
    const float* __restrict__ bo, const float* __restrict__ x, float* __restrict__ out)
{
  __shared__ __align__(16) u16 SH[2 * 128 * 64 + 2 * 64 * 64];
  u16* As = SH; u16* Bs = SH + 2 * 128 * 64;
  f32x4 acc[2][4];
  gemm_nt<128, 64, 64, 4, 1, 2, 4>(att, Wot, 2560, 2560, 2560,
                                   blockIdx.x * 128, 0, acc, As, Bs);
  const int lane = threadIdx.x & 63;
  const int wr = threadIdx.x >> 6;
  float* etf = (float*)SH;   // [64][132] f32 = 33792 B (SH is 48 KB)
  __syncthreads();
  #pragma unroll
  for (int m = 0; m < 2; m++)
    #pragma unroll
    for (int n = 0; n < 4; n++)
      #pragma unroll
      for (int j = 0; j < 4; j++) {
        const int sl = wr * 32 + m * 16 + (lane >> 4) * 4 + j;
        const int c  = n * 16 + (lane & 15);
        etf[c * 132 + sl] = acc[m][n][j];
      }
  __syncthreads();
  const int b = blockIdx.x >> 3, s0 = (blockIdx.x & 7) * 128;
  #pragma unroll
  for (int it = 0; it < 8; ++it) {
    const int task = it * 256 + threadIdx.x;
    const int c = task >> 5, q = (task & 31) * 4;
    const float bias = bo[c];
    f32x4 v = *(const f32x4*)(etf + c * 132 + q);
    const long xi = ((long)(b * 64 + c) << 10) + s0 + q;
    const f32x4 xv = *(const f32x4*)(x + xi);
    #pragma unroll
    for (int e = 0; e < 4; e++) v[e] += bias + xv[e];
    *(f32x4*)(out + xi) = v;
  }
}

// ---------------------------------------------------------------------------
extern "C" void kernel_launch(void* const* d_in, const int* in_sizes, int n_in,
                              void* d_out, int out_size, void* d_ws, size_t ws_size,
                              hipStream_t stream)
{
  (void)in_sizes; (void)n_in; (void)out_size; (void)ws_size;
  const float* x  = (const float*)d_in[0];
  // d_in[1] = t (unused)
  const float* Wp = (const float*)d_in[2];
  const float* bp = (const float*)d_in[3];
  const float* Wo = (const float*)d_in[4];
  const float* bo = (const float*)d_in[5];
  float* out = (float*)d_out;

  char* w8 = (char*)d_ws;
  u16*   P    = (u16*)(w8 + 0L);           // [32][1024][1024] bf16, 64 MB
  u16*   Vt   = (u16*)(w8 + 67108864L);    // [32][640][1024] bf16, 40 MB
  u16*   att  = (u16*)(w8 + 109051904L);   // [8][1024][2560] bf16, 40 MB
  u16*   xt   = (u16*)(w8 + 150994944L);   // [8192][64] bf16
  u16*   Wtp  = (u16*)(w8 + 152043520L);   // [7680][64] bf16
  u16*   Wot  = (u16*)(w8 + 153026560L);   // [64][2560] bf16
  u16*   Wpb  = (u16*)(w8 + 153354240L);   // [64][7680] bf16
  u16*   T    = (u16*)(w8 + 154337280L);   // [32][1024][64] bf16, 4 MB
  u16*   Ahat = (u16*)(w8 + 158531584L);   // [4][64][64] bf16
  float* uh   = (float*)(w8 + 158564352L); // [4][64]
  float* wh   = (float*)(w8 + 158565376L); // [4][64]
  float* ch   = (float*)(w8 + 158566400L); // [4]
  float* ut   = (float*)(w8 + 158566464L); // [32][1024]
  float* wt   = (float*)(w8 + 158697536L); // [32][1024]

  // prep: bf16 copies / transposes
  k_cast<<<240, 256, 0, stream>>>(Wp, Wpb, 61440);
  tr_to_bf16<float><<<dim3(1, 16, 8),  256, 0, stream>>>(x,  xt,  64, 1024, 65536L, 65536L);
  tr_to_bf16<float><<<dim3(1, 120, 1), 256, 0, stream>>>(Wp, Wtp, 64, 7680, 0L, 0L);
  tr_to_bf16<float><<<dim3(40, 1, 1),  256, 0, stream>>>(Wo, Wot, 2560, 64, 0L, 0L);
  // rank-64 QK precompute
  k_prep <<<4,   256, 0, stream>>>(Wpb, Ahat);
  k_prepv<<<1,   256, 0, stream>>>(Wp, bp, uh, wh, ch);
  k_T    <<<dim3(8, 32), 256, 0, stream>>>(xt, Ahat, T);
  k_vecs <<<128, 256, 0, stream>>>(xt, uh, wh, ch, ut, wt);
  // V projection (direct transposed write)
  k_projv<<<dim3(64, 20), 256, 0, stream>>>(xt, Wtp, bp, Vt);
  // P = exp(S*SCALE), unnormalized
  k_qk   <<<2048, 256, 0, stream>>>(T, xt, ut, wt, P);
  // column sums -> fold 1/Z into Vt
  k_colsum_vscale<<<dim3(8, 32), 256, 0, stream>>>(P, Vt);
  // att = P @ Vt^T (normalized via scaled Vt)
  k_pv   <<<1280, 256, 0, stream>>>(P, Vt, att);
  // out projection + residual
  k_out  <<<64,  256, 0, stream>>>(att, Wot, bo, x, out);
}

// Round 5
// 166.642 us; speedup vs baseline: 3.0257x; 1.4121x over previous
//
#include <hip/hip_runtime.h>
#include <hip/hip_bf16.h>
#include <stdint.h>

typedef unsigned short u16;
typedef __attribute__((ext_vector_type(4))) float f32x4;
typedef __attribute__((ext_vector_type(8))) short bf16x8;

#define DEV __device__ __forceinline__

DEV float bf2f(u16 b){ unsigned u = ((unsigned)b) << 16; return __builtin_bit_cast(float, u); }
DEV u16 f2bf(float f){
  unsigned u = __builtin_bit_cast(unsigned, f);
  u += 0x7FFFu + ((u >> 16) & 1u);
  return (u16)(u >> 16);
}
DEV float ldf(const float* p){ return *p; }
DEV float ldf(const u16* p){ return bf2f(*p); }

// XCD-aware block swizzle (T1). Requires nwg % 8 == 0.
DEV int xcd_swz(int nwg){
  const int bid = (int)blockIdx.x;
  return (bid & 7) * (nwg >> 3) + (bid >> 3);
}

// ---------------------------------------------------------------------------
// f32 -> bf16 flat cast, 8 elems/thread
__global__ __launch_bounds__(256) void k_cast(
    const float* __restrict__ s, u16* __restrict__ d, int nchunks)
{
  const int i = blockIdx.x * 256 + threadIdx.x;
  if (i >= nchunks) return;
  const f32x4 a = *(const f32x4*)(s + (long)i * 8);
  const f32x4 b = *(const f32x4*)(s + (long)i * 8 + 4);
  bf16x8 r;
  #pragma unroll
  for (int e = 0; e < 4; e++){ r[e] = (short)f2bf(a[e]); r[e+4] = (short)f2bf(b[e]); }
  *(bf16x8*)(d + (long)i * 8) = r;
}

// Generic 64x64-tile transpose, any->bf16: dst[c][r] = src[r][c]
template<typename T>
__global__ __launch_bounds__(256) void tr_to_bf16(
    const T* __restrict__ src, u16* __restrict__ dst,
    int R, int C, long sB, long dB)
{
  __shared__ float tile[64][65];
  const int b = blockIdx.z;
  src += (long)b * sB;
  dst += (long)b * dB;
  const int r0 = blockIdx.x * 64, c0 = blockIdx.y * 64;
  const int t = threadIdx.x;
  const int rr = t >> 2, cc = (t & 3) * 16;
  const T* sp = src + (long)(r0 + rr) * C + (c0 + cc);
  #pragma unroll
  for (int q = 0; q < 16; q++) tile[rr][cc + q] = ldf(sp + q);
  __syncthreads();
  u16* dp = dst + (long)(c0 + rr) * R + (r0 + cc);
  #pragma unroll
  for (int q = 0; q < 16; q++) dp[q] = f2bf(tile[cc + q][rr]);
}

// ---------------------------------------------------------------------------
// NT GEMM tile core, 2-phase double-buffered + both-sides XOR swizzle.
// C[i][j] = sum_k A[i][k]*B[j][k]; A/B row-major bf16 with leading dims lda/ldb.
template<int BM, int BN, int BK, int WR, int WC, int MF, int NF>
DEV void gemm_nt(const u16* __restrict__ A, const u16* __restrict__ B,
                 int K, long lda, long ldb, int arow0, int brow0,
                 f32x4 (&acc)[MF][NF], u16* As, u16* Bs)
{
  const int tid  = threadIdx.x;
  const int lane = tid & 63;
  const int w    = tid >> 6;
  const int wr   = w / WC, wc = w % WC;
  constexpr int NT   = WR * WC * 64;
  constexpr int AISS = (BM * BK * 2) / (NT * 16);
  constexpr int BISS = (BN * BK * 2) / (NT * 16);
  constexpr int ABUF = BM * BK;
  constexpr int BBUF = BN * BK;

  #pragma unroll
  for (int m = 0; m < MF; m++)
    #pragma unroll
    for (int n = 0; n < NF; n++) acc[m][n] = f32x4{0.f, 0.f, 0.f, 0.f};

  const int frow = lane & 15;
  const int fs   = lane >> 4;

  auto stage = [&](int buf, int kt) {
    #pragma unroll
    for (int q = 0; q < AISS; q++) {
      const int boff = q * NT * 16 + tid * 16;
      const int row  = boff / (BK * 2);
      const int slot = (boff % (BK * 2)) >> 4;
      const int kk   = ((slot ^ (row & 7)) << 3);
      const u16* src = A + (long)(arow0 + row) * lda + kt + kk;
      __builtin_amdgcn_global_load_lds(
          (const __attribute__((address_space(1))) void*)src,
          (__attribute__((address_space(3))) void*)(As + buf * ABUF + (boff >> 1)), 16, 0, 0);
    }
    #pragma unroll
    for (int q = 0; q < BISS; q++) {
      const int boff = q * NT * 16 + tid * 16;
      const int row  = boff / (BK * 2);
      const int slot = (boff % (BK * 2)) >> 4;
      const int kk   = ((slot ^ (row & 7)) << 3);
      const u16* src = B + (long)(brow0 + row) * ldb + kt + kk;
      __builtin_amdgcn_global_load_lds(
          (const __attribute__((address_space(1))) void*)src,
          (__attribute__((address_space(3))) void*)(Bs + buf * BBUF + (boff >> 1)), 16, 0, 0);
    }
  };

  auto compute = [&](int buf) {
    __builtin_amdgcn_s_setprio(1);
    #pragma unroll
    for (int ks = 0; ks < BK / 32; ++ks) {
      bf16x8 af[MF], bfr[NF];
      #pragma unroll
      for (int m = 0; m < MF; m++) {
        const int row  = wr * (MF * 16) + m * 16 + frow;
        const int slot = (ks * 4 + fs) ^ (row & 7);
        af[m] = *(const bf16x8*)(As + buf * ABUF + row * BK + slot * 8);
      }
      #pragma unroll
      for (int n = 0; n < NF; n++) {
        const int row  = wc * (NF * 16) + n * 16 + frow;
        const int slot = (ks * 4 + fs) ^ (row & 7);
        bfr[n] = *(const bf16x8*)(Bs + buf * BBUF + row * BK + slot * 8);
      }
      #pragma unroll
      for (int m = 0; m < MF; m++)
        #pragma unroll
        for (int n = 0; n < NF; n++)
          acc[m][n] = __builtin_amdgcn_mfma_f32_16x16x32_bf16(af[m], bfr[n], acc[m][n], 0, 0, 0);
    }
    __builtin_amdgcn_s_setprio(0);
  };

  stage(0, 0);
  asm volatile("s_waitcnt vmcnt(0)" ::: "memory");
  __syncthreads();
  int cur = 0;
  for (int kt = BK; kt < K; kt += BK) {
    stage(cur ^ 1, kt);
    compute(cur);
    asm volatile("s_waitcnt vmcnt(0)" ::: "memory");
    __syncthreads();
    cur ^= 1;
  }
  compute(cur);
}

// ---------------------------------------------------------------------------
// Per-wave epilogue: stage wave tile (MF*16 x NF*16) bf16 into LDS (chunk-XOR
// swizzled), then coalesced bf16x8 stores via fstore(row, col0, v).
// SH must hold WR*WC * MF*16 * NF*16 u16 (reuses dead As).
template<int MF, int NF, typename FV, typename FS>
DEV void epi_u16(u16* SH, FV&& fval, FS&& fstore)
{
  constexpr int RC = MF * 16, CC = NF * 16, CPR = NF * 2;
  const int lane = threadIdx.x & 63;
  const int w = threadIdx.x >> 6;
  u16* et = SH + w * (RC * CC);
  __syncthreads();                 // all waves done reading As/Bs
  #pragma unroll
  for (int m = 0; m < MF; m++)
    #pragma unroll
    for (int n = 0; n < NF; n++)
      #pragma unroll
      for (int j = 0; j < 4; j++) {
        const int row = m * 16 + (lane >> 4) * 4 + j;
        const int col = n * 16 + (lane & 15);
        et[row * CC + (((col >> 3) ^ row) & (CPR - 1)) * 8 + (col & 7)] =
            f2bf(fval(m, n, j, row, col));
      }
  constexpr int RPI = 64 / CPR;
  #pragma unroll
  for (int it = 0; it < RC / RPI; ++it) {
    const int row = it * RPI + lane / CPR;
    const int ch  = lane % CPR;
    bf16x8 v = *(const bf16x8*)(et + row * CC + ((ch ^ row) & (CPR - 1)) * 8);
    fstore(row, ch * 8, v);
  }
}

// ---------------------------------------------------------------------------
// Ahat[h][e][c] = sum_d Wp[e][kb+d] * Wp[c][qb+d]   (= (Wq Wk^T)^T entry)
__global__ __launch_bounds__(256) void k_prep(
    const u16* __restrict__ Wpb, u16* __restrict__ Ahat)
{
  __shared__ __align__(16) u16 SH[4 * 64 * 64];
  u16* As = SH; u16* Bs = SH + 2 * 64 * 64;
  const int h = blockIdx.x;
  f32x4 acc[2][2];
  gemm_nt<64, 64, 64, 2, 2, 2, 2>(Wpb + h * 1920 + 640, Wpb + h * 1920, 640,
                                  7680, 7680, 0, 0, acc, As, Bs);
  const int w = threadIdx.x >> 6;
  const int wr = w >> 1, wc = w & 1;
  u16* dst = Ahat + h * 4096;
  epi_u16<2, 2>(SH,
    [&](int m, int n, int j, int row, int col){ return acc[m][n][j]; },
    [&](int row, int c0, bf16x8 v){
      *(bf16x8*)(dst + (wr * 32 + row) * 64 + wc * 32 + c0) = v; });
}

// uh[h][c] = Wq[c]·bk  — one wave per (h,c); wt/ch terms cancel in the
// softmax-over-i normalization and are dropped entirely.
__global__ __launch_bounds__(256) void k_prepv(
    const float* __restrict__ Wp, const float* __restrict__ bp,
    float* __restrict__ uh)
{
  const int w = threadIdx.x >> 6, lane = threadIdx.x & 63;
  const int idx = blockIdx.x * 4 + w;   // 0..255
  const int h = idx >> 6, c = idx & 63;
  const int qb = h * 1920, kb = qb + 640;
  const float* wrow = Wp + (long)c * 7680 + qb;
  float s = 0.f;
  #pragma unroll
  for (int d0 = 0; d0 < 640; d0 += 64)
    s += wrow[d0 + lane] * bp[kb + d0 + lane];
  #pragma unroll
  for (int off = 32; off; off >>= 1) s += __shfl_down(s, off);
  if (lane == 0) uh[idx] = s;
}

// T[bh][i][e] = sum_c xt[b*1024+i][c] * Ahat[h][e][c]
__global__ __launch_bounds__(256) void k_T(
    const u16* __restrict__ xt, const u16* __restrict__ Ahat, u16* __restrict__ T)
{
  __shared__ __align__(16) u16 SH[2 * 128 * 64 + 2 * 64 * 64];
  u16* As = SH; u16* Bs = SH + 2 * 128 * 64;
  const int ti = blockIdx.x, bh = blockIdx.y;
  const int b = bh >> 2, h = bh & 3;
  f32x4 acc[2][4];
  gemm_nt<128, 64, 64, 4, 1, 2, 4>(xt, Ahat + h * 4096, 64, 64, 64,
                                   b * 1024 + ti * 128, 0, acc, As, Bs);
  const int wr = threadIdx.x >> 6;
  u16* dst = T + ((long)bh * 1024 + ti * 128 + wr * 32) * 64;
  epi_u16<2, 4>(SH,
    [&](int m, int n, int j, int row, int col){ return acc[m][n][j]; },
    [&](int row, int c0, bf16x8 v){ *(bf16x8*)(dst + (long)row * 64 + c0) = v; });
}

// ut[bh][i] = xt_row · u_h
__global__ __launch_bounds__(256) void k_vecs(
    const u16* __restrict__ xt, const float* __restrict__ uh,
    float* __restrict__ ut)
{
  const int idx = blockIdx.x * 256 + threadIdx.x;  // 32768
  const int bh = idx >> 10, i = idx & 1023;
  const int b = bh >> 2, h = bh & 3;
  const u16* xr = xt + ((long)b * 1024 + i) * 64;
  const float* u = uh + h * 64;
  float su = 0.f;
  #pragma unroll
  for (int c8 = 0; c8 < 8; ++c8) {
    bf16x8 v = *(const bf16x8*)(xr + c8 * 8);
    #pragma unroll
    for (int e = 0; e < 8; e++) su += bf2f((u16)v[e]) * u[c8 * 8 + e];
  }
  ut[idx] = su;
}

// P[bh][i][j] = exp(SCALE * (T_i · x_j + ut[i]))   (unnormalized)
// + per-tile column partial sums Zp[bh][ti][j]
__global__ __launch_bounds__(256) void k_qk(
    const u16* __restrict__ T, const u16* __restrict__ xt,
    const float* __restrict__ ut, u16* __restrict__ P, float* __restrict__ Zp)
{
  __shared__ __align__(16) u16 SH[4 * 128 * 64];
  __shared__ float Zs[2][128];
  u16* As = SH; u16* Bs = SH + 2 * 128 * 64;
  const int id = xcd_swz(2048);
  const int bh = id >> 6, ti = (id & 63) >> 3, tj = id & 7;
  const int b = bh >> 2;
  f32x4 acc[4][4];
  gemm_nt<128, 128, 64, 2, 2, 4, 4>(T + (long)bh * 65536, xt, 64, 64, 64,
                                    ti * 128, b * 1024 + tj * 128, acc, As, Bs);
  const int lane = threadIdx.x & 63;
  const int w = threadIdx.x >> 6;
  const int wr = w >> 1, wc = w & 1;
  const int gi0 = ti * 128 + wr * 64, gj0 = tj * 128 + wc * 64;
  const float* utp = ut + (bh << 10);
  float rv[4][4];
  #pragma unroll
  for (int m = 0; m < 4; m++)
    #pragma unroll
    for (int j = 0; j < 4; j++) rv[m][j] = utp[gi0 + m * 16 + (lane >> 4) * 4 + j];
  u16* dst = P + ((long)bh << 20);
  float csum[4] = {0.f, 0.f, 0.f, 0.f};
  epi_u16<4, 4>(SH,
    [&](int m, int n, int j, int row, int col){
      const float v = __expf((acc[m][n][j] + rv[m][j]) * 0.03952847075210474f);
      csum[n] += v;
      return v;
    },
    [&](int row, int c0, bf16x8 v){
      *(bf16x8*)(dst + (long)(gi0 + row) * 1024 + gj0 + c0) = v; });
  // column partials: reduce over the 4 lane-groups, then over wr via LDS
  #pragma unroll
  for (int n = 0; n < 4; n++) {
    csum[n] += __shfl_xor(csum[n], 16);
    csum[n] += __shfl_xor(csum[n], 32);
  }
  if ((lane >> 4) == 0) {
    #pragma unroll
    for (int n = 0; n < 4; n++) Zs[wr][wc * 64 + n * 16 + lane] = csum[n];
  }
  __syncthreads();
  const int t = threadIdx.x;
  if (t < 128)
    Zp[((long)bh * 8 + ti) * 1024 + tj * 128 + t] = Zs[0][t] + Zs[1][t];
}

// V projection, written directly transposed: Vt[bh][d][s] (bf16, +bias)
__global__ __launch_bounds__(256) void k_projv(
    const u16* __restrict__ xt, const u16* __restrict__ Wtp,
    const float* __restrict__ bp, u16* __restrict__ Vt)
{
  __shared__ __align__(16) u16 SH[4 * 128 * 64];
  u16* As = SH; u16* Bs = SH + 2 * 128 * 64;
  const int bx = blockIdx.x, by = blockIdx.y;
  const int h = by / 5, d0 = (by % 5) * 128;
  const int vb = h * 1920 + 1280 + d0;
  f32x4 acc[4][4];
  gemm_nt<128, 128, 64, 2, 2, 4, 4>(xt, Wtp, 64, 64, 64, bx * 128, vb, acc, As, Bs);
  const int lane = threadIdx.x & 63;
  const int w = threadIdx.x >> 6;
  const int wr = w >> 1, wc = w & 1;
  const int b = bx >> 3, s0 = (bx & 7) * 128;
  float bv[4];
  #pragma unroll
  for (int n = 0; n < 4; n++) bv[n] = bp[vb + wc * 64 + n * 16 + (lane & 15)];
  u16* etb = SH;   // 128 x 128 u16 = 32 KB, block-wide transposed tile
  __syncthreads();
  #pragma unroll
  for (int m = 0; m < 4; m++)
    #pragma unroll
    for (int n = 0; n < 4; n++)
      #pragma unroll
      for (int j = 0; j < 4; j++) {
        const int sl = wr * 64 + m * 16 + (lane >> 4) * 4 + j;  // s_local
        const int dl = wc * 64 + n * 16 + (lane & 15);          // d_local
        etb[dl * 128 + (((sl >> 3) ^ dl) & 15) * 8 + (sl & 7)] = f2bf(acc[m][n][j] + bv[n]);
      }
  __syncthreads();
  const long base = ((long)(b * 4 + h) * 640 + d0) * 1024 + s0;
  #pragma unroll
  for (int it = 0; it < 8; ++it) {
    const int task = it * 256 + threadIdx.x;
    const int d = task >> 4, chk = task & 15;
    bf16x8 v = *(const bf16x8*)(etb + d * 128 + ((chk ^ d) & 15) * 8);
    *(bf16x8*)(Vt + base + (long)d * 1024 + chk * 8) = v;
  }
}

// Z[j] = sum over 8 Zp partials; Vt[bh][*][j] *= 1/Z[j]  (in place)
__global__ __launch_bounds__(256) void k_vscale(
    const float* __restrict__ Zp, u16* __restrict__ Vt)
{
  __shared__ float Wl[128];
  const int jb = blockIdx.x, bh = blockIdx.y;
  const int t = threadIdx.x, jc = t & 15, rg = t >> 4;
  if (t < 128) {
    float Z = 0.f;
    #pragma unroll
    for (int k = 0; k < 8; k++) Z += Zp[((long)bh * 8 + k) * 1024 + jb * 128 + t];
    Wl[t] = 1.0f / Z;
  }
  __syncthreads();
  float wv[8];
  #pragma unroll
  for (int e = 0; e < 8; e++) wv[e] = Wl[jc * 8 + e];
  u16* Vp = Vt + (long)bh * 655360 + jb * 128 + jc * 8;
  for (int d = rg; d < 640; d += 16) {
    bf16x8 v = *(const bf16x8*)(Vp + (long)d * 1024);
    bf16x8 r;
    #pragma unroll
    for (int e = 0; e < 8; e++) r[e] = (short)f2bf(bf2f((u16)v[e]) * wv[e]);
    *(bf16x8*)(Vp + (long)d * 1024) = r;
  }
}

// att[b][s][h*640+d] = sum_j P[i][j] * Vt[d][j]   (Vt pre-scaled by 1/Z)
__global__ __launch_bounds__(256) void k_pv(
    const u16* __restrict__ P, const u16* __restrict__ Vt, u16* __restrict__ att)
{
  __shared__ __align__(16) u16 SH[4 * 128 * 64];
  u16* As = SH; u16* Bs = SH + 2 * 128 * 64;
  const int id = xcd_swz(1280);
  const int bh = id / 40;
  const int rem = id - bh * 40;
  const int ti = rem & 7, td = rem >> 3;
  f32x4 acc[4][4];
  gemm_nt<128, 128, 64, 2, 2, 4, 4>(P + ((long)bh << 20), Vt + (long)bh * 655360, 1024,
                                    1024, 1024, ti * 128, td * 128, acc, As, Bs);
  const int w = threadIdx.x >> 6;
  const int wr = w >> 1, wc = w & 1;
  const int b = bh >> 2, h = bh & 3;
  const int gi0 = ti * 128 + wr * 64, gd0 = td * 128 + wc * 64;
  epi_u16<4, 4>(SH,
    [&](int m, int n, int j, int row, int col){ return acc[m][n][j]; },
    [&](int row, int c0, bf16x8 v){
      *(bf16x8*)(att + ((long)(b << 10) + gi0 + row) * 2560 + h * 640 + gd0 + c0) = v; });
}

// out[b][c][s] = att @ Wo^T + bo + x   (f32, fused residual, coalesced stores)
__global__ __launch_bounds__(256) void k_out(
    const u16* __restrict__ att, const u16* __restrict__ Wot,
    const float* __restrict__ bo, const float* __restrict__ x, float* __restrict__ out)
{
  __shared__ __align__(16) u16 SH[2 * 128 * 64 + 2 * 64 * 64];
  u16* As = SH; u16* Bs = SH + 2 * 128 * 64;
  f32x4 acc[2][4];
  gemm_nt<128, 64, 64, 4, 1, 2, 4>(att, Wot, 2560, 2560, 2560,
                                   blockIdx.x * 128, 0, acc, As, Bs);
  const int lane = threadIdx.x & 63;
  const int wr = threadIdx.x >> 6;
  float* etf = (float*)SH;   // [64][132] f32 = 33792 B (SH is 48 KB)
  __syncthreads();
  #pragma unroll
  for (int m = 0; m < 2; m++)
    #pragma unroll
    for (int n = 0; n < 4; n++)
      #pragma unroll
      for (int j = 0; j < 4; j++) {
        const int sl = wr * 32 + m * 16 + (lane >> 4) * 4 + j;
        const int c  = n * 16 + (lane & 15);
        etf[c * 132 + sl] = acc[m][n][j];
      }
  __syncthreads();
  const int b = blockIdx.x >> 3, s0 = (blockIdx.x & 7) * 128;
  #pragma unroll
  for (int it = 0; it < 8; ++it) {
    const int task = it * 256 + threadIdx.x;
    const int c = task >> 5, q = (task & 31) * 4;
    const float bias = bo[c];
    f32x4 v = *(const f32x4*)(etf + c * 132 + q);
    const long xi = ((long)(b * 64 + c) << 10) + s0 + q;
    const f32x4 xv = *(const f32x4*)(x + xi);
    #pragma unroll
    for (int e = 0; e < 4; e++) v[e] += bias + xv[e];
    *(f32x4*)(out + xi) = v;
  }
}

// ---------------------------------------------------------------------------
extern "C" void kernel_launch(void* const* d_in, const int* in_sizes, int n_in,
                              void* d_out, int out_size, void* d_ws, size_t ws_size,
                              hipStream_t stream)
{
  (void)in_sizes; (void)n_in; (void)out_size; (void)ws_size;
  const float* x  = (const float*)d_in[0];
  // d_in[1] = t (unused)
  const float* Wp = (const float*)d_in[2];
  const float* bp = (const float*)d_in[3];
  const float* Wo = (const float*)d_in[4];
  const float* bo = (const float*)d_in[5];
  float* out = (float*)d_out;

  char* w8 = (char*)d_ws;
  u16*   P    = (u16*)(w8 + 0L);           // [32][1024][1024] bf16, 64 MB
  u16*   Vt   = (u16*)(w8 + 67108864L);    // [32][640][1024] bf16, 40 MB
  u16*   att  = (u16*)(w8 + 109051904L);   // [8][1024][2560] bf16, 40 MB
  u16*   xt   = (u16*)(w8 + 150994944L);   // [8192][64] bf16
  u16*   Wtp  = (u16*)(w8 + 152043520L);   // [7680][64] bf16
  u16*   Wot  = (u16*)(w8 + 153026560L);   // [64][2560] bf16
  u16*   Wpb  = (u16*)(w8 + 153354240L);   // [64][7680] bf16
  u16*   T    = (u16*)(w8 + 154337280L);   // [32][1024][64] bf16, 4 MB
  u16*   Ahat = (u16*)(w8 + 158531584L);   // [4][64][64] bf16
  float* uh   = (float*)(w8 + 158564352L); // [4][64]
  float* ut   = (float*)(w8 + 158565376L); // [32][1024]
  float* Zp   = (float*)(w8 + 158696448L); // [32][8][1024] f32, 1 MB

  // prep: bf16 copies / transposes
  k_cast<<<240, 256, 0, stream>>>(Wp, Wpb, 61440);
  tr_to_bf16<float><<<dim3(1, 16, 8),  256, 0, stream>>>(x,  xt,  64, 1024, 65536L, 65536L);
  tr_to_bf16<float><<<dim3(1, 120, 1), 256, 0, stream>>>(Wp, Wtp, 64, 7680, 0L, 0L);
  tr_to_bf16<float><<<dim3(40, 1, 1),  256, 0, stream>>>(Wo, Wot, 2560, 64, 0L, 0L);
  // rank-64 QK precompute
  k_prep <<<4,   256, 0, stream>>>(Wpb, Ahat);
  k_prepv<<<64,  256, 0, stream>>>(Wp, bp, uh);
  k_T    <<<dim3(8, 32), 256, 0, stream>>>(xt, Ahat, T);
  k_vecs <<<128, 256, 0, stream>>>(xt, uh, ut);
  // V projection (direct transposed write)
  k_projv<<<dim3(64, 20), 256, 0, stream>>>(xt, Wtp, bp, Vt);
  // P = exp(S*SCALE), unnormalized, + column partial sums
  k_qk   <<<2048, 256, 0, stream>>>(T, xt, ut, P, Zp);
  // Z reduce -> fold 1/Z into Vt
  k_vscale<<<dim3(8, 32), 256, 0, stream>>>(Zp, Vt);
  // att = P @ Vt^T (normalized via scaled Vt)
  k_pv   <<<1280, 256, 0, stream>>>(P, Vt, att);
  // out projection + residual
  k_out  <<<64,  256, 0, stream>>>(att, Wot, bo, x, out);
}

// Round 6
// 134.938 us; speedup vs baseline: 3.7366x; 1.2350x over previous
//
#include <hip/hip_runtime.h>
#include <hip/hip_bf16.h>
#include <stdint.h>

typedef unsigned short u16;
typedef __attribute__((ext_vector_type(4))) float f32x4;
typedef __attribute__((ext_vector_type(8))) short bf16x8;

#define DEV __device__ __forceinline__

DEV float bf2f(u16 b){ unsigned u = ((unsigned)b) << 16; return __builtin_bit_cast(float, u); }
DEV u16 f2bf(float f){
  unsigned u = __builtin_bit_cast(unsigned, f);
  u += 0x7FFFu + ((u >> 16) & 1u);
  return (u16)(u >> 16);
}
DEV float ldf(const float* p){ return *p; }
DEV float ldf(const u16* p){ return bf2f(*p); }

// XCD-aware block swizzle (T1). Requires nwg % 8 == 0.
DEV int xcd_swz(int nwg){
  const int bid = (int)blockIdx.x;
  return (bid & 7) * (nwg >> 3) + (bid >> 3);
}

// ---------------------------------------------------------------------------
// 64-col-chunk transpose helper: dst[c][r] = src[r][c] (f32 -> bf16)
DEV void tr_tile(float (*tile)[65], const float* src, u16* dst,
                 int R, int C, int r0, int c0)
{
  const int t = threadIdx.x;
  const int rr = t >> 2, cc = (t & 3) * 16;
  const float* sp = src + (long)(r0 + rr) * C + (c0 + cc);
  #pragma unroll
  for (int q = 0; q < 16; q++) tile[rr][cc + q] = sp[q];
  __syncthreads();
  u16* dp = dst + (long)(c0 + rr) * R + (r0 + cc);
  #pragma unroll
  for (int q = 0; q < 16; q++) dp[q] = f2bf(tile[cc + q][rr]);
}

// Consolidated prep: Wp->bf16 flat | x^T | Wp^T | Wo^T | uh = Wq^T bk
__global__ __launch_bounds__(256) void k_misc(
    const float* __restrict__ x, const float* __restrict__ Wp,
    const float* __restrict__ Wo, const float* __restrict__ bp,
    u16* __restrict__ xt, u16* __restrict__ Wtp, u16* __restrict__ Wot,
    u16* __restrict__ Wpb, float* __restrict__ uh)
{
  __shared__ float tile[64][65];
  const int q = blockIdx.x;
  if (q < 240) {                      // Wp -> Wpb (bf16 flat cast)
    const long i = (long)q * 256 + threadIdx.x;
    const f32x4 a = *(const f32x4*)(Wp + i * 8);
    const f32x4 b = *(const f32x4*)(Wp + i * 8 + 4);
    bf16x8 r;
    #pragma unroll
    for (int e = 0; e < 4; e++){ r[e] = (short)f2bf(a[e]); r[e+4] = (short)f2bf(b[e]); }
    *(bf16x8*)(Wpb + i * 8) = r;
  } else if (q < 368) {               // x -> xt  (per-batch 64x1024 transpose)
    const int p = q - 240, c0 = (p & 15) * 64, b = p >> 4;
    tr_tile(tile, x + (long)b * 65536, xt + (long)b * 65536, 64, 1024, 0, c0);
  } else if (q < 488) {               // Wp -> Wtp
    const int p = q - 368;
    tr_tile(tile, Wp, Wtp, 64, 7680, 0, p * 64);
  } else if (q < 528) {               // Wo -> Wot
    const int p = q - 488;
    tr_tile(tile, Wo, Wot, 2560, 64, p * 64, 0);
  } else {                            // uh[h][c] = Wq[c] . bk   (one wave each)
    const int p = q - 528;
    const int wv = threadIdx.x >> 6, lane = threadIdx.x & 63;
    const int idx = p * 4 + wv;       // 0..255
    const int h = idx >> 6, c = idx & 63;
    const int qb = h * 1920, kb = qb + 640;
    const float* wrow = Wp + (long)c * 7680 + qb;
    float s = 0.f;
    #pragma unroll
    for (int d0 = 0; d0 < 640; d0 += 64)
      s += wrow[d0 + lane] * bp[kb + d0 + lane];
    #pragma unroll
    for (int off = 32; off; off >>= 1) s += __shfl_down(s, off);
    if (lane == 0) uh[idx] = s;
  }
}

// ---------------------------------------------------------------------------
// NT GEMM tile core, 2-phase double-buffered + both-sides XOR swizzle.
// C[i][j] = sum_k A[i][k]*B[j][k]; A/B row-major bf16 with leading dims lda/ldb.
template<int BM, int BN, int BK, int WR, int WC, int MF, int NF>
DEV void gemm_nt(const u16* __restrict__ A, const u16* __restrict__ B,
                 int K, long lda, long ldb, int arow0, int brow0,
                 f32x4 (&acc)[MF][NF], u16* As, u16* Bs)
{
  const int tid  = threadIdx.x;
  const int lane = tid & 63;
  const int w    = tid >> 6;
  const int wr   = w / WC, wc = w % WC;
  constexpr int NT   = WR * WC * 64;
  constexpr int AISS = (BM * BK * 2) / (NT * 16);
  constexpr int BISS = (BN * BK * 2) / (NT * 16);
  constexpr int ABUF = BM * BK;
  constexpr int BBUF = BN * BK;

  #pragma unroll
  for (int m = 0; m < MF; m++)
    #pragma unroll
    for (int n = 0; n < NF; n++) acc[m][n] = f32x4{0.f, 0.f, 0.f, 0.f};

  const int frow = lane & 15;
  const int fs   = lane >> 4;

  auto stage = [&](int buf, int kt) {
    #pragma unroll
    for (int q = 0; q < AISS; q++) {
      const int boff = q * NT * 16 + tid * 16;
      const int row  = boff / (BK * 2);
      const int slot = (boff % (BK * 2)) >> 4;
      const int kk   = ((slot ^ (row & 7)) << 3);
      const u16* src = A + (long)(arow0 + row) * lda + kt + kk;
      __builtin_amdgcn_global_load_lds(
          (const __attribute__((address_space(1))) void*)src,
          (__attribute__((address_space(3))) void*)(As + buf * ABUF + (boff >> 1)), 16, 0, 0);
    }
    #pragma unroll
    for (int q = 0; q < BISS; q++) {
      const int boff = q * NT * 16 + tid * 16;
      const int row  = boff / (BK * 2);
      const int slot = (boff % (BK * 2)) >> 4;
      const int kk   = ((slot ^ (row & 7)) << 3);
      const u16* src = B + (long)(brow0 + row) * ldb + kt + kk;
      __builtin_amdgcn_global_load_lds(
          (const __attribute__((address_space(1))) void*)src,
          (__attribute__((address_space(3))) void*)(Bs + buf * BBUF + (boff >> 1)), 16, 0, 0);
    }
  };

  auto compute = [&](int buf) {
    __builtin_amdgcn_s_setprio(1);
    #pragma unroll
    for (int ks = 0; ks < BK / 32; ++ks) {
      bf16x8 af[MF], bfr[NF];
      #pragma unroll
      for (int m = 0; m < MF; m++) {
        const int row  = wr * (MF * 16) + m * 16 + frow;
        const int slot = (ks * 4 + fs) ^ (row & 7);
        af[m] = *(const bf16x8*)(As + buf * ABUF + row * BK + slot * 8);
      }
      #pragma unroll
      for (int n = 0; n < NF; n++) {
        const int row  = wc * (NF * 16) + n * 16 + frow;
        const int slot = (ks * 4 + fs) ^ (row & 7);
        bfr[n] = *(const bf16x8*)(Bs + buf * BBUF + row * BK + slot * 8);
      }
      #pragma unroll
      for (int m = 0; m < MF; m++)
        #pragma unroll
        for (int n = 0; n < NF; n++)
          acc[m][n] = __builtin_amdgcn_mfma_f32_16x16x32_bf16(af[m], bfr[n], acc[m][n], 0, 0, 0);
    }
    __builtin_amdgcn_s_setprio(0);
  };

  stage(0, 0);
  asm volatile("s_waitcnt vmcnt(0)" ::: "memory");
  __syncthreads();
  int cur = 0;
  for (int kt = BK; kt < K; kt += BK) {
    stage(cur ^ 1, kt);
    compute(cur);
    asm volatile("s_waitcnt vmcnt(0)" ::: "memory");
    __syncthreads();
    cur ^= 1;
  }
  compute(cur);
}

// ---------------------------------------------------------------------------
// Per-wave epilogue: stage wave tile (MF*16 x NF*16) bf16 into LDS (chunk-XOR
// swizzled), then coalesced bf16x8 stores via fstore(row, col0, v).
template<int MF, int NF, typename FV, typename FS>
DEV void epi_u16(u16* SH, FV&& fval, FS&& fstore)
{
  constexpr int RC = MF * 16, CC = NF * 16, CPR = NF * 2;
  const int lane = threadIdx.x & 63;
  const int w = threadIdx.x >> 6;
  u16* et = SH + w * (RC * CC);
  __syncthreads();                 // all waves done reading As/Bs
  #pragma unroll
  for (int m = 0; m < MF; m++)
    #pragma unroll
    for (int n = 0; n < NF; n++)
      #pragma unroll
      for (int j = 0; j < 4; j++) {
        const int row = m * 16 + (lane >> 4) * 4 + j;
        const int col = n * 16 + (lane & 15);
        et[row * CC + (((col >> 3) ^ row) & (CPR - 1)) * 8 + (col & 7)] =
            f2bf(fval(m, n, j, row, col));
      }
  constexpr int RPI = 64 / CPR;
  #pragma unroll
  for (int it = 0; it < RC / RPI; ++it) {
    const int row = it * RPI + lane / CPR;
    const int ch  = lane % CPR;
    bf16x8 v = *(const bf16x8*)(et + row * CC + ((ch ^ row) & (CPR - 1)) * 8);
    fstore(row, ch * 8, v);
  }
}

// ---------------------------------------------------------------------------
// Ahat[h][e][c] = sum_d Wp[e][kb+d] * Wp[c][qb+d]
__global__ __launch_bounds__(256) void k_prep(
    const u16* __restrict__ Wpb, u16* __restrict__ Ahat)
{
  __shared__ __align__(16) u16 SH[4 * 64 * 64];
  u16* As = SH; u16* Bs = SH + 2 * 64 * 64;
  const int h = blockIdx.x;
  f32x4 acc[2][2];
  gemm_nt<64, 64, 64, 2, 2, 2, 2>(Wpb + h * 1920 + 640, Wpb + h * 1920, 640,
                                  7680, 7680, 0, 0, acc, As, Bs);
  const int w = threadIdx.x >> 6;
  const int wr = w >> 1, wc = w & 1;
  u16* dst = Ahat + h * 4096;
  epi_u16<2, 2>(SH,
    [&](int m, int n, int j, int row, int col){ return acc[m][n][j]; },
    [&](int row, int c0, bf16x8 v){
      *(bf16x8*)(dst + (wr * 32 + row) * 64 + wc * 32 + c0) = v; });
}

// ---------------------------------------------------------------------------
// Fused QK: P[bh][i][j] = exp(SCALE*((xt_i @ Ahat_h) . xt_j + ut_i)), with
// the T-tile (128x64) computed in-kernel into LDS (no global T round-trip),
// ut from the same LDS tile, plus per-tile column partial sums Zp.
__global__ __launch_bounds__(256) void k_qk(
    const u16* __restrict__ xt, const u16* __restrict__ Ahat,
    const float* __restrict__ uh, u16* __restrict__ P, float* __restrict__ Zp)
{
  __shared__ __align__(16) u16 SH[128*64 + 64*64 + 128*64];  // XI | AH | XJ
  __shared__ float uts[128];
  __shared__ float uhl[64];
  __shared__ float Zs[2][128];
  u16* XI = SH;              // xt i-tile, later reused to hold the T-tile
  u16* AH = SH + 8192;
  u16* XJ = SH + 12288;
  const int tid = threadIdx.x, lane = tid & 63, w = tid >> 6;
  const int id = xcd_swz(2048);
  const int bh = id >> 6, ti = (id & 63) >> 3, tj = id & 7;
  const int b = bh >> 2, h = bh & 3;
  const int i0 = b * 1024 + ti * 128;
  const int j0 = b * 1024 + tj * 128;

  // stage XI, AH, XJ (linear LDS dest, source-slot XOR pre-swizzle)
  #pragma unroll
  for (int q = 0; q < 4; q++) {
    const int boff = q * 4096 + tid * 16;
    const int row = boff >> 7, slot = (boff & 127) >> 4;
    const int kk = (slot ^ (row & 7)) << 3;
    __builtin_amdgcn_global_load_lds(
        (const __attribute__((address_space(1))) void*)(xt + (long)(i0 + row) * 64 + kk),
        (__attribute__((address_space(3))) void*)(XI + (boff >> 1)), 16, 0, 0);
  }
  #pragma unroll
  for (int q = 0; q < 2; q++) {
    const int boff = q * 4096 + tid * 16;
    const int row = boff >> 7, slot = (boff & 127) >> 4;
    const int kk = (slot ^ (row & 7)) << 3;
    __builtin_amdgcn_global_load_lds(
        (const __attribute__((address_space(1))) void*)(Ahat + h * 4096 + row * 64 + kk),
        (__attribute__((address_space(3))) void*)(AH + (boff >> 1)), 16, 0, 0);
  }
  #pragma unroll
  for (int q = 0; q < 4; q++) {
    const int boff = q * 4096 + tid * 16;
    const int row = boff >> 7, slot = (boff & 127) >> 4;
    const int kk = (slot ^ (row & 7)) << 3;
    __builtin_amdgcn_global_load_lds(
        (const __attribute__((address_space(1))) void*)(xt + (long)(j0 + row) * 64 + kk),
        (__attribute__((address_space(3))) void*)(XJ + (boff >> 1)), 16, 0, 0);
  }
  if (tid < 64) uhl[tid] = uh[h * 64 + tid];
  asm volatile("s_waitcnt vmcnt(0)" ::: "memory");
  __syncthreads();

  const int frow = lane & 15, fs = lane >> 4;
  const int wr = w >> 1, wc = w & 1;

  // GEMM1: T[128][64] = XI @ AH^T  (waves 2x2, per-wave 64x32)
  f32x4 acc1[4][2];
  #pragma unroll
  for (int m = 0; m < 4; m++)
    #pragma unroll
    for (int n = 0; n < 2; n++) acc1[m][n] = f32x4{0.f, 0.f, 0.f, 0.f};
  #pragma unroll
  for (int ks = 0; ks < 2; ks++) {
    bf16x8 af[4], bfr[2];
    #pragma unroll
    for (int m = 0; m < 4; m++) {
      const int row = wr * 64 + m * 16 + frow;
      af[m] = *(const bf16x8*)(XI + row * 64 + (((ks * 4 + fs) ^ (row & 7)) << 3));
    }
    #pragma unroll
    for (int n = 0; n < 2; n++) {
      const int row = wc * 32 + n * 16 + frow;
      bfr[n] = *(const bf16x8*)(AH + row * 64 + (((ks * 4 + fs) ^ (row & 7)) << 3));
    }
    #pragma unroll
    for (int m = 0; m < 4; m++)
      #pragma unroll
      for (int n = 0; n < 2; n++)
        acc1[m][n] = __builtin_amdgcn_mfma_f32_16x16x32_bf16(af[m], bfr[n], acc1[m][n], 0, 0, 0);
  }
  // ut[i] = xt_i . uh   (128 threads, vector LDS reads)
  float su = 0.f;
  if (tid < 128) {
    #pragma unroll
    for (int s = 0; s < 8; s++) {
      bf16x8 v = *(const bf16x8*)(XI + tid * 64 + ((s ^ (tid & 7)) << 3));
      #pragma unroll
      for (int e = 0; e < 8; e++) su += bf2f((u16)v[e]) * uhl[s * 8 + e];
    }
  }
  __syncthreads();           // all XI/AH reads complete
  if (tid < 128) uts[tid] = su;
  // write T-tile (bf16) over XI in the same swizzled [row][64] layout
  #pragma unroll
  for (int m = 0; m < 4; m++)
    #pragma unroll
    for (int n = 0; n < 2; n++)
      #pragma unroll
      for (int j = 0; j < 4; j++) {
        const int row = wr * 64 + m * 16 + (lane >> 4) * 4 + j;
        const int col = wc * 32 + n * 16 + (lane & 15);
        XI[row * 64 + (((col >> 3) ^ (row & 7)) << 3) + (col & 7)] = f2bf(acc1[m][n][j]);
      }
  __syncthreads();

  // GEMM2: S = T @ XJ^T  (waves 2x2, per-wave 64x64)
  f32x4 acc[4][4];
  #pragma unroll
  for (int m = 0; m < 4; m++)
    #pragma unroll
    for (int n = 0; n < 4; n++) acc[m][n] = f32x4{0.f, 0.f, 0.f, 0.f};
  #pragma unroll
  for (int ks = 0; ks < 2; ks++) {
    bf16x8 af[4], bfr[4];
    #pragma unroll
    for (int m = 0; m < 4; m++) {
      const int row = wr * 64 + m * 16 + frow;
      af[m] = *(const bf16x8*)(XI + row * 64 + (((ks * 4 + fs) ^ (row & 7)) << 3));
    }
    #pragma unroll
    for (int n = 0; n < 4; n++) {
      const int row = wc * 64 + n * 16 + frow;
      bfr[n] = *(const bf16x8*)(XJ + row * 64 + (((ks * 4 + fs) ^ (row & 7)) << 3));
    }
    #pragma unroll
    for (int m = 0; m < 4; m++)
      #pragma unroll
      for (int n = 0; n < 4; n++)
        acc[m][n] = __builtin_amdgcn_mfma_f32_16x16x32_bf16(af[m], bfr[n], acc[m][n], 0, 0, 0);
  }

  // epilogue: exp + coalesced P stores + column partial sums
  const int gi0 = ti * 128 + wr * 64, gj0 = tj * 128 + wc * 64;
  float rv[4][4];
  #pragma unroll
  for (int m = 0; m < 4; m++)
    #pragma unroll
    for (int j = 0; j < 4; j++) rv[m][j] = uts[wr * 64 + m * 16 + (lane >> 4) * 4 + j];
  u16* dst = P + ((long)bh << 20);
  float csum[4] = {0.f, 0.f, 0.f, 0.f};
  epi_u16<4, 4>(SH,
    [&](int m, int n, int j, int row, int col){
      const float v = __expf((acc[m][n][j] + rv[m][j]) * 0.03952847075210474f);
      csum[n] += v;
      return v;
    },
    [&](int row, int c0, bf16x8 v){
      *(bf16x8*)(dst + (long)(gi0 + row) * 1024 + gj0 + c0) = v; });
  #pragma unroll
  for (int n = 0; n < 4; n++) {
    csum[n] += __shfl_xor(csum[n], 16);
    csum[n] += __shfl_xor(csum[n], 32);
  }
  if ((lane >> 4) == 0) {
    #pragma unroll
    for (int n = 0; n < 4; n++) Zs[wr][wc * 64 + n * 16 + lane] = csum[n];
  }
  __syncthreads();
  if (tid < 128)
    Zp[((long)bh * 8 + ti) * 1024 + tj * 128 + tid] = Zs[0][tid] + Zs[1][tid];
}

// ---------------------------------------------------------------------------
// V projection with fused 1/Z scaling, written directly transposed:
// Vt[bh][d][s] = (x W_v + b_v)^T * (1/Z[s])
__global__ __launch_bounds__(256) void k_projv(
    const u16* __restrict__ xt, const u16* __restrict__ Wtp,
    const float* __restrict__ bp, const float* __restrict__ Zp,
    u16* __restrict__ Vt)
{
  __shared__ __align__(16) u16 SH[4 * 128 * 64];
  __shared__ float Wl[128];
  u16* As = SH; u16* Bs = SH + 2 * 128 * 64;
  const int bx = blockIdx.x, by = blockIdx.y;
  const int h = by / 5, d0 = (by % 5) * 128;
  const int vb = h * 1920 + 1280 + d0;
  f32x4 acc[4][4];
  gemm_nt<128, 128, 64, 2, 2, 4, 4>(xt, Wtp, 64, 64, 64, bx * 128, vb, acc, As, Bs);
  const int lane = threadIdx.x & 63;
  const int w = threadIdx.x >> 6;
  const int wr = w >> 1, wc = w & 1;
  const int b = bx >> 3, s0 = (bx & 7) * 128;
  const int t = threadIdx.x;
  if (t < 128) {
    float Z = 0.f;
    #pragma unroll
    for (int k = 0; k < 8; k++) Z += Zp[((long)(b * 4 + h) * 8 + k) * 1024 + s0 + t];
    Wl[t] = 1.0f / Z;
  }
  float bv[4];
  #pragma unroll
  for (int n = 0; n < 4; n++) bv[n] = bp[vb + wc * 64 + n * 16 + (lane & 15)];
  u16* etb = SH;   // 128 x 128 u16 block-wide transposed tile
  __syncthreads();
  #pragma unroll
  for (int m = 0; m < 4; m++)
    #pragma unroll
    for (int n = 0; n < 4; n++)
      #pragma unroll
      for (int j = 0; j < 4; j++) {
        const int sl = wr * 64 + m * 16 + (lane >> 4) * 4 + j;  // s_local
        const int dl = wc * 64 + n * 16 + (lane & 15);          // d_local
        etb[dl * 128 + (((sl >> 3) ^ dl) & 15) * 8 + (sl & 7)] =
            f2bf((acc[m][n][j] + bv[n]) * Wl[sl]);
      }
  __syncthreads();
  const long base = ((long)(b * 4 + h) * 640 + d0) * 1024 + s0;
  #pragma unroll
  for (int it = 0; it < 8; ++it) {
    const int task = it * 256 + threadIdx.x;
    const int d = task >> 4, chk = task & 15;
    bf16x8 v = *(const bf16x8*)(etb + d * 128 + ((chk ^ d) & 15) * 8);
    *(bf16x8*)(Vt + base + (long)d * 1024 + chk * 8) = v;
  }
}

// att[b][s][h*640+d] = sum_j P[i][j] * Vt[d][j]   (Vt pre-scaled by 1/Z)
__global__ __launch_bounds__(256) void k_pv(
    const u16* __restrict__ P, const u16* __restrict__ Vt, u16* __restrict__ att)
{
  __shared__ __align__(16) u16 SH[4 * 128 * 64];
  u16* As = SH; u16* Bs = SH + 2 * 128 * 64;
  const int id = xcd_swz(1280);
  const int bh = id / 40;
  const int rem = id - bh * 40;
  const int ti = rem & 7, td = rem >> 3;
  f32x4 acc[4][4];
  gemm_nt<128, 128, 64, 2, 2, 4, 4>(P + ((long)bh << 20), Vt + (long)bh * 655360, 1024,
                                    1024, 1024, ti * 128, td * 128, acc, As, Bs);
  const int w = threadIdx.x >> 6;
  const int wr = w >> 1, wc = w & 1;
  const int b = bh >> 2, h = bh & 3;
  const int gi0 = ti * 128 + wr * 64, gd0 = td * 128 + wc * 64;
  epi_u16<4, 4>(SH,
    [&](int m, int n, int j, int row, int col){ return acc[m][n][j]; },
    [&](int row, int c0, bf16x8 v){
      *(bf16x8*)(att + ((long)(b << 10) + gi0 + row) * 2560 + h * 640 + gd0 + c0) = v; });
}

// out[b][c][s] = att @ Wo^T + bo + x   (f32, fused residual, coalesced stores)
__global__ __launch_bounds__(256) void k_out(
    const u16* __restrict__ att, const u16* __restrict__ Wot,
    const float* __restrict__ bo, const float* __restrict__ x, float* __restrict__ out)
{
  __shared__ __align__(16) u16 SH[2 * 128 * 64 + 2 * 64 * 64];
  u16* As = SH; u16* Bs = SH + 2 * 128 * 64;
  f32x4 acc[2][4];
  gemm_nt<128, 64, 64, 4, 1, 2, 4>(att, Wot, 2560, 2560, 2560,
                                   blockIdx.x * 128, 0, acc, As, Bs);
  const int lane = threadIdx.x & 63;
  const int wr = threadIdx.x >> 6;
  float* etf = (float*)SH;   // [64][132] f32
  __syncthreads();
  #pragma unroll
  for (int m = 0; m < 2; m++)
    #pragma unroll
    for (int n = 0; n < 4; n++)
      #pragma unroll
      for (int j = 0; j < 4; j++) {
        const int sl = wr * 32 + m * 16 + (lane >> 4) * 4 + j;
        const int c  = n * 16 + (lane & 15);
        etf[c * 132 + sl] = acc[m][n][j];
      }
  __syncthreads();
  const int b = blockIdx.x >> 3, s0 = (blockIdx.x & 7) * 128;
  #pragma unroll
  for (int it = 0; it < 8; ++it) {
    const int task = it * 256 + threadIdx.x;
    const int c = task >> 5, q = (task & 31) * 4;
    const float bias = bo[c];
    f32x4 v = *(const f32x4*)(etf + c * 132 + q);
    const long xi = ((long)(b * 64 + c) << 10) + s0 + q;
    const f32x4 xv = *(const f32x4*)(x + xi);
    #pragma unroll
    for (int e = 0; e < 4; e++) v[e] += bias + xv[e];
    *(f32x4*)(out + xi) = v;
  }
}

// ---------------------------------------------------------------------------
extern "C" void kernel_launch(void* const* d_in, const int* in_sizes, int n_in,
                              void* d_out, int out_size, void* d_ws, size_t ws_size,
                              hipStream_t stream)
{
  (void)in_sizes; (void)n_in; (void)out_size; (void)ws_size;
  const float* x  = (const float*)d_in[0];
  // d_in[1] = t (unused)
  const float* Wp = (const float*)d_in[2];
  const float* bp = (const float*)d_in[3];
  const float* Wo = (const float*)d_in[4];
  const float* bo = (const float*)d_in[5];
  float* out = (float*)d_out;

  char* w8 = (char*)d_ws;
  u16*   P    = (u16*)(w8 + 0L);           // [32][1024][1024] bf16, 64 MB
  u16*   Vt   = (u16*)(w8 + 67108864L);    // [32][640][1024] bf16, 40 MB
  u16*   att  = (u16*)(w8 + 109051904L);   // [8][1024][2560] bf16, 40 MB
  u16*   xt   = (u16*)(w8 + 150994944L);   // [8192][64] bf16
  u16*   Wtp  = (u16*)(w8 + 152043520L);   // [7680][64] bf16
  u16*   Wot  = (u16*)(w8 + 153026560L);   // [64][2560] bf16
  u16*   Wpb  = (u16*)(w8 + 153354240L);   // [64][7680] bf16
  u16*   Ahat = (u16*)(w8 + 154337280L);   // [4][64][64] bf16
  float* uh   = (float*)(w8 + 154370048L); // [4][64]
  float* Zp   = (float*)(w8 + 154371072L); // [32][8][1024] f32, 1 MB

  k_misc <<<592, 256, 0, stream>>>(x, Wp, Wo, bp, xt, Wtp, Wot, Wpb, uh);
  k_prep <<<4,   256, 0, stream>>>(Wpb, Ahat);
  k_qk   <<<2048, 256, 0, stream>>>(xt, Ahat, uh, P, Zp);
  k_projv<<<dim3(64, 20), 256, 0, stream>>>(xt, Wtp, bp, Zp, Vt);
  k_pv   <<<1280, 256, 0, stream>>>(P, Vt, att);
  k_out  <<<64,  256, 0, stream>>>(att, Wot, bo, x, out);
}

// Round 7
// 76.735 us; speedup vs baseline: 6.5707x; 1.7585x over previous
//
#include <hip/hip_runtime.h>
#include <hip/hip_bf16.h>
#include <stdint.h>

typedef unsigned short u16;
typedef __attribute__((ext_vector_type(4))) float f32x4;
typedef __attribute__((ext_vector_type(8))) short bf16x8;

#define DEV __device__ __forceinline__

DEV float bf2f(u16 b){ unsigned u = ((unsigned)b) << 16; return __builtin_bit_cast(float, u); }
DEV u16 f2bf(float f){
  unsigned u = __builtin_bit_cast(unsigned, f);
  u += 0x7FFFu + ((u >> 16) & 1u);
  return (u16)(u >> 16);
}

// XCD-aware block swizzle (T1). Requires nwg % 8 == 0.
DEV int xcd_swz(int nwg){
  const int bid = (int)blockIdx.x;
  return (bid & 7) * (nwg >> 3) + (bid >> 3);
}

// stage a 128x64 bf16 tile (rows from srcbase, row-major lda=64) into LDS,
// linear dest + source-slot XOR pre-swizzle (slots of 8 u16, XOR row&7)
DEV void stage_x64(const u16* srcbase, u16* dst, int tid){
  #pragma unroll
  for (int q = 0; q < 4; q++) {
    const int boff = q * 4096 + tid * 16;
    const int row = boff >> 7, slot = (boff & 127) >> 4;
    const int kk = (slot ^ (row & 7)) << 3;
    __builtin_amdgcn_global_load_lds(
        (const __attribute__((address_space(1))) void*)(srcbase + (long)row * 64 + kk),
        (__attribute__((address_space(3))) void*)(dst + (boff >> 1)), 16, 0, 0);
  }
}

// 64x64-tile transpose helper: dst[c][r] = src[r][c] (f32 -> bf16)
DEV void tr_tile(float (*tile)[65], const float* src, u16* dst,
                 int R, int C, int r0, int c0)
{
  const int t = threadIdx.x;
  const int rr = t >> 2, cc = (t & 3) * 16;
  const float* sp = src + (long)(r0 + rr) * C + (c0 + cc);
  #pragma unroll
  for (int q = 0; q < 16; q++) tile[rr][cc + q] = sp[q];
  __syncthreads();
  u16* dp = dst + (long)(c0 + rr) * R + (r0 + cc);
  #pragma unroll
  for (int q = 0; q < 16; q++) dp[q] = f2bf(tile[cc + q][rr]);
}

// ---------------------------------------------------------------------------
// Consolidated prep: Wp->bf16 | x^T | Wo^T | uh = Wq^T bk | x->bf16 + ones row
__global__ __launch_bounds__(256) void k_misc(
    const float* __restrict__ x, const float* __restrict__ Wp,
    const float* __restrict__ Wo, const float* __restrict__ bp,
    u16* __restrict__ xt, u16* __restrict__ Wot, u16* __restrict__ Wpb,
    u16* __restrict__ xb, float* __restrict__ uh)
{
  __shared__ float tile[64][65];
  const int q = blockIdx.x;
  if (q < 240) {                      // Wp -> Wpb (bf16 flat cast)
    const long i = (long)q * 256 + threadIdx.x;
    const f32x4 a = *(const f32x4*)(Wp + i * 8);
    const f32x4 b = *(const f32x4*)(Wp + i * 8 + 4);
    bf16x8 r;
    #pragma unroll
    for (int e = 0; e < 4; e++){ r[e] = (short)f2bf(a[e]); r[e+4] = (short)f2bf(b[e]); }
    *(bf16x8*)(Wpb + i * 8) = r;
  } else if (q < 368) {               // x -> xt (per-batch 64x1024 transpose)
    const int p = q - 240, c0 = (p & 15) * 64, b = p >> 4;
    tr_tile(tile, x + (long)b * 65536, xt + (long)b * 65536, 64, 1024, 0, c0);
  } else if (q < 408) {               // Wo -> Wot
    const int p = q - 368;
    tr_tile(tile, Wo, Wot, 2560, 64, p * 64, 0);
  } else if (q < 472) {               // uh[h][c] = Wq[c] . bk (one wave each)
    const int p = q - 408;
    const int wv = threadIdx.x >> 6, lane = threadIdx.x & 63;
    const int idx = p * 4 + wv;       // 0..255
    const int h = idx >> 6, c = idx & 63;
    const int qb = h * 1920, kb = qb + 640;
    const float* wrow = Wp + (long)c * 7680 + qb;
    float s = 0.f;
    #pragma unroll
    for (int d0 = 0; d0 < 640; d0 += 64)
      s += wrow[d0 + lane] * bp[kb + d0 + lane];
    #pragma unroll
    for (int off = 32; off; off >>= 1) s += __shfl_down(s, off);
    if (lane == 0) uh[idx] = s;
  } else {                            // x -> xb [8][80][1024] bf16; row64=1, 65-79=0
    const int ch = (q - 472) * 256 + threadIdx.x;     // 81920 chunks of 8
    const int b = ch / 10240, rem = ch % 10240;
    const int row = rem >> 7, j8 = rem & 127;
    bf16x8 r;
    if (row < 64) {
      const float* sp = x + ((long)b * 64 + row) * 1024 + j8 * 8;
      const f32x4 a = *(const f32x4*)sp;
      const f32x4 bb = *(const f32x4*)(sp + 4);
      #pragma unroll
      for (int e = 0; e < 4; e++){ r[e] = (short)f2bf(a[e]); r[e+4] = (short)f2bf(bb[e]); }
    } else if (row == 64) {
      #pragma unroll
      for (int e = 0; e < 8; e++) r[e] = (short)0x3F80;   // 1.0 bf16
    } else {
      #pragma unroll
      for (int e = 0; e < 8; e++) r[e] = 0;
    }
    *(bf16x8*)(xb + ((long)b * 80 + row) * 1024 + j8 * 8) = r;
  }
}

// nh row of MxT: MxT[c'][h*80+64] = sum_d bv[d]*Wo[h*640+d][c']; cols 65-79 = 0
__global__ __launch_bounds__(256) void k_nh(
    const u16* __restrict__ Wot, const float* __restrict__ bp,
    u16* __restrict__ MxT)
{
  const int wv = threadIdx.x >> 6, lane = threadIdx.x & 63;
  const int idx = blockIdx.x * 4 + wv;   // 0..255
  const int h = idx >> 6, cp = idx & 63;
  const u16* wr_ = Wot + (long)cp * 2560 + h * 640;
  const float* bv = bp + h * 1920 + 1280;
  float s = 0.f;
  #pragma unroll
  for (int d0 = 0; d0 < 640; d0 += 64)
    s += bf2f(wr_[d0 + lane]) * bv[d0 + lane];
  #pragma unroll
  for (int off = 32; off; off >>= 1) s += __shfl_down(s, off);
  if (lane == 0) MxT[cp * 320 + h * 80 + 64] = f2bf(s);
  if (lane >= 1 && lane < 16) MxT[cp * 320 + h * 80 + 64 + lane] = 0;
}

// ---------------------------------------------------------------------------
// NT GEMM tile core, 2-phase double-buffered + both-sides XOR swizzle.
template<int BM, int BN, int BK, int WR, int WC, int MF, int NF>
DEV void gemm_nt(const u16* __restrict__ A, const u16* __restrict__ B,
                 int K, long lda, long ldb, int arow0, int brow0,
                 f32x4 (&acc)[MF][NF], u16* As, u16* Bs)
{
  const int tid  = threadIdx.x;
  const int lane = tid & 63;
  const int w    = tid >> 6;
  const int wr   = w / WC, wc = w % WC;
  constexpr int NT   = WR * WC * 64;
  constexpr int AISS = (BM * BK * 2) / (NT * 16);
  constexpr int BISS = (BN * BK * 2) / (NT * 16);
  constexpr int ABUF = BM * BK;
  constexpr int BBUF = BN * BK;

  #pragma unroll
  for (int m = 0; m < MF; m++)
    #pragma unroll
    for (int n = 0; n < NF; n++) acc[m][n] = f32x4{0.f, 0.f, 0.f, 0.f};

  const int frow = lane & 15;
  const int fs   = lane >> 4;

  auto stage = [&](int buf, int kt) {
    #pragma unroll
    for (int q = 0; q < AISS; q++) {
      const int boff = q * NT * 16 + tid * 16;
      const int row  = boff / (BK * 2);
      const int slot = (boff % (BK * 2)) >> 4;
      const int kk   = ((slot ^ (row & 7)) << 3);
      const u16* src = A + (long)(arow0 + row) * lda + kt + kk;
      __builtin_amdgcn_global_load_lds(
          (const __attribute__((address_space(1))) void*)src,
          (__attribute__((address_space(3))) void*)(As + buf * ABUF + (boff >> 1)), 16, 0, 0);
    }
    #pragma unroll
    for (int q = 0; q < BISS; q++) {
      const int boff = q * NT * 16 + tid * 16;
      const int row  = boff / (BK * 2);
      const int slot = (boff % (BK * 2)) >> 4;
      const int kk   = ((slot ^ (row & 7)) << 3);
      const u16* src = B + (long)(brow0 + row) * ldb + kt + kk;
      __builtin_amdgcn_global_load_lds(
          (const __attribute__((address_space(1))) void*)src,
          (__attribute__((address_space(3))) void*)(Bs + buf * BBUF + (boff >> 1)), 16, 0, 0);
    }
  };

  auto compute = [&](int buf) {
    __builtin_amdgcn_s_setprio(1);
    #pragma unroll
    for (int ks = 0; ks < BK / 32; ++ks) {
      bf16x8 af[MF], bfr[NF];
      #pragma unroll
      for (int m = 0; m < MF; m++) {
        const int row  = wr * (MF * 16) + m * 16 + frow;
        const int slot = (ks * 4 + fs) ^ (row & 7);
        af[m] = *(const bf16x8*)(As + buf * ABUF + row * BK + slot * 8);
      }
      #pragma unroll
      for (int n = 0; n < NF; n++) {
        const int row  = wc * (NF * 16) + n * 16 + frow;
        const int slot = (ks * 4 + fs) ^ (row & 7);
        bfr[n] = *(const bf16x8*)(Bs + buf * BBUF + row * BK + slot * 8);
      }
      #pragma unroll
      for (int m = 0; m < MF; m++)
        #pragma unroll
        for (int n = 0; n < NF; n++)
          acc[m][n] = __builtin_amdgcn_mfma_f32_16x16x32_bf16(af[m], bfr[n], acc[m][n], 0, 0, 0);
    }
    __builtin_amdgcn_s_setprio(0);
  };

  stage(0, 0);
  asm volatile("s_waitcnt vmcnt(0)" ::: "memory");
  __syncthreads();
  int cur = 0;
  for (int kt = BK; kt < K; kt += BK) {
    stage(cur ^ 1, kt);
    compute(cur);
    asm volatile("s_waitcnt vmcnt(0)" ::: "memory");
    __syncthreads();
    cur ^= 1;
  }
  compute(cur);
}

// Per-wave epilogue: stage wave tile into LDS swizzled, coalesced bf16x8 stores
template<int MF, int NF, typename FV, typename FS>
DEV void epi_u16(u16* SH, FV&& fval, FS&& fstore)
{
  constexpr int RC = MF * 16, CC = NF * 16, CPR = NF * 2;
  const int lane = threadIdx.x & 63;
  const int w = threadIdx.x >> 6;
  u16* et = SH + w * (RC * CC);
  __syncthreads();
  #pragma unroll
  for (int m = 0; m < MF; m++)
    #pragma unroll
    for (int n = 0; n < NF; n++)
      #pragma unroll
      for (int j = 0; j < 4; j++) {
        const int row = m * 16 + (lane >> 4) * 4 + j;
        const int col = n * 16 + (lane & 15);
        et[row * CC + (((col >> 3) ^ row) & (CPR - 1)) * 8 + (col & 7)] =
            f2bf(fval(m, n, j, row, col));
      }
  constexpr int RPI = 64 / CPR;
  #pragma unroll
  for (int it = 0; it < RC / RPI; ++it) {
    const int row = it * RPI + lane / CPR;
    const int ch  = lane % CPR;
    bf16x8 v = *(const bf16x8*)(et + row * CC + ((ch ^ row) & (CPR - 1)) * 8);
    fstore(row, ch * 8, v);
  }
}

// ---------------------------------------------------------------------------
// k_prep: blocks 0-3: Ahat[h] = Wk_h @ Wq_h^T (rank-64 S matrix)
//         blocks 4-7: MxT[c'][h*80+c] = (Wv_h @ Wo_h)[c][c']
__global__ __launch_bounds__(256) void k_prep(
    const u16* __restrict__ Wpb, const u16* __restrict__ Wot,
    u16* __restrict__ Ahat, u16* __restrict__ MxT)
{
  __shared__ __align__(16) u16 SH[4 * 64 * 64];
  u16* As = SH; u16* Bs = SH + 2 * 64 * 64;
  const int q = blockIdx.x;
  const int w = threadIdx.x >> 6;
  const int wr = w >> 1, wc = w & 1;
  f32x4 acc[2][2];
  if (q < 4) {
    const int h = q;
    gemm_nt<64, 64, 64, 2, 2, 2, 2>(Wpb + h * 1920 + 640, Wpb + h * 1920, 640,
                                    7680, 7680, 0, 0, acc, As, Bs);
    u16* dst = Ahat + h * 4096;
    epi_u16<2, 2>(SH,
      [&](int m, int n, int j, int row, int col){ return acc[m][n][j]; },
      [&](int row, int c0, bf16x8 v){
        *(bf16x8*)(dst + (wr * 32 + row) * 64 + wc * 32 + c0) = v; });
  } else {
    const int h = q - 4;
    gemm_nt<64, 64, 64, 2, 2, 2, 2>(Wot + h * 640, Wpb + h * 1920 + 1280, 640,
                                    2560, 7680, 0, 0, acc, As, Bs);
    epi_u16<2, 2>(SH,
      [&](int m, int n, int j, int row, int col){ return acc[m][n][j]; },
      [&](int row, int c0, bf16x8 v){
        *(bf16x8*)(MxT + (long)(wr * 32 + row) * 320 + h * 80 + wc * 32 + c0) = v; });
  }
}

// ---------------------------------------------------------------------------
// Pass 1: Z[bh][j] = sum_i exp(SCALE*(T_i.x_j + ut_i)). No P store.
// grid 256 = (bh, tj); per block loop over 8 i-tiles, T recomputed in LDS.
__global__ __launch_bounds__(256) void k_qkz(
    const u16* __restrict__ xt, const u16* __restrict__ Ahat,
    const float* __restrict__ uh, float* __restrict__ Z)
{
  __shared__ __align__(16) u16 XI[2][8192];
  __shared__ __align__(16) u16 AH[4096];
  __shared__ __align__(16) u16 XJ[8192];
  __shared__ __align__(16) u16 TT[8192];
  __shared__ float uts[128];
  __shared__ float uhl[64];
  __shared__ float Zs[2][128];
  const int tid = threadIdx.x, lane = tid & 63, w = tid >> 6;
  const int frow = lane & 15, fs = lane >> 4;
  const int wr = w >> 1, wc = w & 1;
  const int id = xcd_swz(256);
  const int bh = id >> 3, tj = id & 7;
  const int b = bh >> 2, h = bh & 3;
  const int j0 = b * 1024 + tj * 128;

  #pragma unroll
  for (int q = 0; q < 2; q++) {       // AH
    const int boff = q * 4096 + tid * 16;
    const int row = boff >> 7, slot = (boff & 127) >> 4;
    const int kk = (slot ^ (row & 7)) << 3;
    __builtin_amdgcn_global_load_lds(
        (const __attribute__((address_space(1))) void*)(Ahat + h * 4096 + row * 64 + kk),
        (__attribute__((address_space(3))) void*)(AH + (boff >> 1)), 16, 0, 0);
  }
  stage_x64(xt + (long)j0 * 64, XJ, tid);
  stage_x64(xt + (long)(b * 1024) * 64, XI[0], tid);
  if (tid < 64) uhl[tid] = uh[h * 64 + tid];
  asm volatile("s_waitcnt vmcnt(0)" ::: "memory");
  __syncthreads();

  float csum[4] = {0.f, 0.f, 0.f, 0.f};
  int cur = 0;
  for (int it = 0; it < 8; ++it) {
    if (it < 7) stage_x64(xt + (long)(b * 1024 + (it + 1) * 128) * 64, XI[cur ^ 1], tid);
    // T-gemm: T = XI[cur] @ AH^T (wave 64x32)
    f32x4 acc1[4][2];
    #pragma unroll
    for (int m = 0; m < 4; m++)
      #pragma unroll
      for (int n = 0; n < 2; n++) acc1[m][n] = f32x4{0.f, 0.f, 0.f, 0.f};
    #pragma unroll
    for (int ks = 0; ks < 2; ks++) {
      bf16x8 af[4], bfr[2];
      #pragma unroll
      for (int m = 0; m < 4; m++) {
        const int row = wr * 64 + m * 16 + frow;
        af[m] = *(const bf16x8*)(XI[cur] + row * 64 + (((ks * 4 + fs) ^ (row & 7)) << 3));
      }
      #pragma unroll
      for (int n = 0; n < 2; n++) {
        const int row = wc * 32 + n * 16 + frow;
        bfr[n] = *(const bf16x8*)(AH + row * 64 + (((ks * 4 + fs) ^ (row & 7)) << 3));
      }
      #pragma unroll
      for (int m = 0; m < 4; m++)
        #pragma unroll
        for (int n = 0; n < 2; n++)
          acc1[m][n] = __builtin_amdgcn_mfma_f32_16x16x32_bf16(af[m], bfr[n], acc1[m][n], 0, 0, 0);
    }
    float su = 0.f;
    if (tid < 128) {
      #pragma unroll
      for (int s = 0; s < 8; s++) {
        bf16x8 v = *(const bf16x8*)(XI[cur] + tid * 64 + ((s ^ (tid & 7)) << 3));
        #pragma unroll
        for (int e = 0; e < 8; e++) su += bf2f((u16)v[e]) * uhl[s * 8 + e];
      }
    }
    __syncthreads();                 // prev S-gemm TT reads + prev exp uts reads done
    if (tid < 128) uts[tid] = su;
    #pragma unroll
    for (int m = 0; m < 4; m++)
      #pragma unroll
      for (int n = 0; n < 2; n++)
        #pragma unroll
        for (int j = 0; j < 4; j++) {
          const int row = wr * 64 + m * 16 + (lane >> 4) * 4 + j;
          const int col = wc * 32 + n * 16 + (lane & 15);
          TT[row * 64 + (((col >> 3) ^ (row & 7)) << 3) + (col & 7)] = f2bf(acc1[m][n][j]);
        }
    asm volatile("s_waitcnt vmcnt(0)" ::: "memory");
    __syncthreads();                 // TT/uts visible; XI[cur^1] landed
    // S-gemm: S = TT @ XJ^T (wave 64x64), then exp+csum
    f32x4 sacc[4][4];
    #pragma unroll
    for (int m = 0; m < 4; m++)
      #pragma unroll
      for (int n = 0; n < 4; n++) sacc[m][n] = f32x4{0.f, 0.f, 0.f, 0.f};
    #pragma unroll
    for (int ks = 0; ks < 2; ks++) {
      bf16x8 af[4], bfr[4];
      #pragma unroll
      for (int m = 0; m < 4; m++) {
        const int row = wr * 64 + m * 16 + frow;
        af[m] = *(const bf16x8*)(TT + row * 64 + (((ks * 4 + fs) ^ (row & 7)) << 3));
      }
      #pragma unroll
      for (int n = 0; n < 4; n++) {
        const int row = wc * 64 + n * 16 + frow;
        bfr[n] = *(const bf16x8*)(XJ + row * 64 + (((ks * 4 + fs) ^ (row & 7)) << 3));
      }
      #pragma unroll
      for (int m = 0; m < 4; m++)
        #pragma unroll
        for (int n = 0; n < 4; n++)
          sacc[m][n] = __builtin_amdgcn_mfma_f32_16x16x32_bf16(af[m], bfr[n], sacc[m][n], 0, 0, 0);
    }
    #pragma unroll
    for (int m = 0; m < 4; m++)
      #pragma unroll
      for (int j = 0; j < 4; j++) {
        const float rv = uts[wr * 64 + m * 16 + (lane >> 4) * 4 + j];
        #pragma unroll
        for (int n = 0; n < 4; n++)
          csum[n] += __expf((sacc[m][n][j] + rv) * 0.03952847075210474f);
      }
    cur ^= 1;
  }
  #pragma unroll
  for (int n = 0; n < 4; n++) {
    csum[n] += __shfl_xor(csum[n], 16);
    csum[n] += __shfl_xor(csum[n], 32);
  }
  if ((lane >> 4) == 0) {
    #pragma unroll
    for (int n = 0; n < 4; n++) Zs[wr][wc * 64 + n * 16 + lane] = csum[n];
  }
  __syncthreads();
  if (tid < 128) Z[(long)bh * 1024 + tj * 128 + tid] = Zs[0][tid] + Zs[1][tid];
}

// ---------------------------------------------------------------------------
// Pass 2: G[b*1024+i][h*80+c] = sum_j Ptilde[i][j] * xb[b][c][j]
// Ptilde = exp(SCALE*(T_i.x_j + ut_i)) / Z[j], recomputed tile-wise in LDS.
// grid 256 = (bh, ti).
__global__ __launch_bounds__(256) void k_G(
    const u16* __restrict__ xt, const u16* __restrict__ xb,
    const u16* __restrict__ Ahat, const float* __restrict__ uh,
    const float* __restrict__ Z, u16* __restrict__ G)
{
  __shared__ __align__(16) u16 XIT[8192];    // XI, then T
  __shared__ __align__(16) u16 AH[4096];
  __shared__ __align__(16) u16 XJ[2][8192];
  __shared__ __align__(16) u16 XB[10240];    // [80][128]
  __shared__ __align__(16) u16 PT[16384];    // P-tile [128][128]; reused for G staging
  __shared__ float uts[128];
  __shared__ float uhl[64];
  __shared__ float rzs[128];
  const int tid = threadIdx.x, lane = tid & 63, w = tid >> 6;
  const int frow = lane & 15, fs = lane >> 4;
  const int wr = w >> 1, wc = w & 1;
  const int id = xcd_swz(256);
  const int bh = id >> 3, ti = id & 7;
  const int b = bh >> 2, h = bh & 3;
  const int i0 = b * 1024 + ti * 128;

  #pragma unroll
  for (int q = 0; q < 2; q++) {       // AH
    const int boff = q * 4096 + tid * 16;
    const int row = boff >> 7, slot = (boff & 127) >> 4;
    const int kk = (slot ^ (row & 7)) << 3;
    __builtin_amdgcn_global_load_lds(
        (const __attribute__((address_space(1))) void*)(Ahat + h * 4096 + row * 64 + kk),
        (__attribute__((address_space(3))) void*)(AH + (boff >> 1)), 16, 0, 0);
  }
  stage_x64(xt + (long)i0 * 64, XIT, tid);
  stage_x64(xt + (long)(b * 1024) * 64, XJ[0], tid);
  if (tid < 64) uhl[tid] = uh[h * 64 + tid];
  asm volatile("s_waitcnt vmcnt(0)" ::: "memory");
  __syncthreads();

  // T-gemm + ut
  f32x4 acc1[4][2];
  #pragma unroll
  for (int m = 0; m < 4; m++)
    #pragma unroll
    for (int n = 0; n < 2; n++) acc1[m][n] = f32x4{0.f, 0.f, 0.f, 0.f};
  #pragma unroll
  for (int ks = 0; ks < 2; ks++) {
    bf16x8 af[4], bfr[2];
    #pragma unroll
    for (int m = 0; m < 4; m++) {
      const int row = wr * 64 + m * 16 + frow;
      af[m] = *(const bf16x8*)(XIT + row * 64 + (((ks * 4 + fs) ^ (row & 7)) << 3));
    }
    #pragma unroll
    for (int n = 0; n < 2; n++) {
      const int row = wc * 32 + n * 16 + frow;
      bfr[n] = *(const bf16x8*)(AH + row * 64 + (((ks * 4 + fs) ^ (row & 7)) << 3));
    }
    #pragma unroll
    for (int m = 0; m < 4; m++)
      #pragma unroll
      for (int n = 0; n < 2; n++)
        acc1[m][n] = __builtin_amdgcn_mfma_f32_16x16x32_bf16(af[m], bfr[n], acc1[m][n], 0, 0, 0);
  }
  float su = 0.f;
  if (tid < 128) {
    #pragma unroll
    for (int s = 0; s < 8; s++) {
      bf16x8 v = *(const bf16x8*)(XIT + tid * 64 + ((s ^ (tid & 7)) << 3));
      #pragma unroll
      for (int e = 0; e < 8; e++) su += bf2f((u16)v[e]) * uhl[s * 8 + e];
    }
  }
  __syncthreads();                   // all XIT reads done
  if (tid < 128) uts[tid] = su;
  #pragma unroll
  for (int m = 0; m < 4; m++)        // write T over XIT
    #pragma unroll
    for (int n = 0; n < 2; n++)
      #pragma unroll
      for (int j = 0; j < 4; j++) {
        const int row = wr * 64 + m * 16 + (lane >> 4) * 4 + j;
        const int col = wc * 32 + n * 16 + (lane & 15);
        XIT[row * 64 + (((col >> 3) ^ (row & 7)) << 3) + (col & 7)] = f2bf(acc1[m][n][j]);
      }
  __syncthreads();                   // T/uts visible

  f32x4 gacc[2][5];
  #pragma unroll
  for (int m = 0; m < 2; m++)
    #pragma unroll
    for (int n = 0; n < 5; n++) gacc[m][n] = f32x4{0.f, 0.f, 0.f, 0.f};
  int cur = 0;
  for (int j = 0; j < 8; ++j) {
    // stage XB(j): [80][128] from xb[b][c][j*128..]
    #pragma unroll
    for (int q = 0; q < 5; q++) {
      const int boff = q * 4096 + tid * 16;
      const int c = boff >> 8, sl = (boff & 255) >> 4;
      const int kk = (sl ^ (c & 7)) << 3;
      __builtin_amdgcn_global_load_lds(
          (const __attribute__((address_space(1))) void*)(xb + ((long)b * 80 + c) * 1024 + j * 128 + kk),
          (__attribute__((address_space(3))) void*)(XB + (boff >> 1)), 16, 0, 0);
    }
    if (j < 7) stage_x64(xt + (long)(b * 1024 + (j + 1) * 128) * 64, XJ[cur ^ 1], tid);
    if (tid < 128) rzs[tid] = 1.0f / Z[(long)bh * 1024 + j * 128 + tid];
    // S-gemm: S = T @ XJ[cur]^T (wave 64x64)
    f32x4 sacc[4][4];
    #pragma unroll
    for (int m = 0; m < 4; m++)
      #pragma unroll
      for (int n = 0; n < 4; n++) sacc[m][n] = f32x4{0.f, 0.f, 0.f, 0.f};
    #pragma unroll
    for (int ks = 0; ks < 2; ks++) {
      bf16x8 af[4], bfr[4];
      #pragma unroll
      for (int m = 0; m < 4; m++) {
        const int row = wr * 64 + m * 16 + frow;
        af[m] = *(const bf16x8*)(XIT + row * 64 + (((ks * 4 + fs) ^ (row & 7)) << 3));
      }
      #pragma unroll
      for (int n = 0; n < 4; n++) {
        const int row = wc * 64 + n * 16 + frow;
        bfr[n] = *(const bf16x8*)(XJ[cur] + row * 64 + (((ks * 4 + fs) ^ (row & 7)) << 3));
      }
      #pragma unroll
      for (int m = 0; m < 4; m++)
        #pragma unroll
        for (int n = 0; n < 4; n++)
          sacc[m][n] = __builtin_amdgcn_mfma_f32_16x16x32_bf16(af[m], bfr[n], sacc[m][n], 0, 0, 0);
    }
    __syncthreads();                 // rzs visible; PT free (prev G done)
    #pragma unroll
    for (int m = 0; m < 4; m++)
      #pragma unroll
      for (int jj = 0; jj < 4; jj++) {
        const int row = wr * 64 + m * 16 + (lane >> 4) * 4 + jj;
        const float rv = uts[row];
        #pragma unroll
        for (int n = 0; n < 4; n++) {
          const int col = wc * 64 + n * 16 + (lane & 15);
          const float p = __expf((sacc[m][n][jj] + rv) * 0.03952847075210474f) * rzs[col];
          PT[row * 128 + (((col >> 3) ^ (row & 7)) << 3) + (col & 7)] = f2bf(p);
        }
      }
    asm volatile("s_waitcnt vmcnt(0)" ::: "memory");   // XB(j), XJ[next] landed
    __syncthreads();                 // P visible
    // G-gemm: gacc += P @ XB^T-view (wave rows w*32..+32, cols 0..79, K=128)
    #pragma unroll
    for (int ks = 0; ks < 4; ks++) {
      bf16x8 af2[2], bfr2[5];
      #pragma unroll
      for (int m = 0; m < 2; m++) {
        const int row = w * 32 + m * 16 + frow;
        af2[m] = *(const bf16x8*)(PT + row * 128 + (((ks * 4 + fs) ^ (row & 7)) << 3));
      }
      #pragma unroll
      for (int n = 0; n < 5; n++) {
        const int rc = n * 16 + frow;
        bfr2[n] = *(const bf16x8*)(XB + rc * 128 + (((ks * 4 + fs) ^ (rc & 7)) << 3));
      }
      #pragma unroll
      for (int m = 0; m < 2; m++)
        #pragma unroll
        for (int n = 0; n < 5; n++)
          gacc[m][n] = __builtin_amdgcn_mfma_f32_16x16x32_bf16(af2[m], bfr2[n], gacc[m][n], 0, 0, 0);
    }
    __syncthreads();                 // all P/XB reads done before overwrite
    cur ^= 1;
  }
  // stage G-tile [128][80] in PT (dead), then coalesced stores
  #pragma unroll
  for (int m = 0; m < 2; m++)
    #pragma unroll
    for (int n = 0; n < 5; n++)
      #pragma unroll
      for (int jj = 0; jj < 4; jj++) {
        const int row = w * 32 + m * 16 + (lane >> 4) * 4 + jj;
        const int col = n * 16 + (lane & 15);
        PT[row * 80 + col] = f2bf(gacc[m][n][jj]);
      }
  __syncthreads();
  #pragma unroll
  for (int it = 0; it < 5; ++it) {
    const int task = it * 256 + tid;
    const int row = task / 10, ch = task % 10;
    bf16x8 v = *(const bf16x8*)(PT + row * 80 + ch * 8);
    *(bf16x8*)(G + (long)(i0 + row) * 320 + h * 80 + ch * 8) = v;
  }
}

// ---------------------------------------------------------------------------
// out[b][c][s] = G @ MxT^T + bo + x  (f32, fused residual, coalesced stores)
__global__ __launch_bounds__(256) void k_out(
    const u16* __restrict__ G, const u16* __restrict__ MxT,
    const float* __restrict__ bo, const float* __restrict__ x, float* __restrict__ out)
{
  __shared__ __align__(16) u16 SH[2 * 128 * 64 + 2 * 64 * 64];
  u16* As = SH; u16* Bs = SH + 2 * 128 * 64;
  f32x4 acc[2][4];
  gemm_nt<128, 64, 64, 4, 1, 2, 4>(G, MxT, 320, 320, 320,
                                   blockIdx.x * 128, 0, acc, As, Bs);
  const int lane = threadIdx.x & 63;
  const int wr = threadIdx.x >> 6;
  float* etf = (float*)SH;   // [64][132] f32
  __syncthreads();
  #pragma unroll
  for (int m = 0; m < 2; m++)
    #pragma unroll
    for (int n = 0; n < 4; n++)
      #pragma unroll
      for (int j = 0; j < 4; j++) {
        const int sl = wr * 32 + m * 16 + (lane >> 4) * 4 + j;
        const int c  = n * 16 + (lane & 15);
        etf[c * 132 + sl] = acc[m][n][j];
      }
  __syncthreads();
  const int b = blockIdx.x >> 3, s0 = (blockIdx.x & 7) * 128;
  #pragma unroll
  for (int it = 0; it < 8; ++it) {
    const int task = it * 256 + threadIdx.x;
    const int c = task >> 5, q = (task & 31) * 4;
    const float bias = bo[c];
    f32x4 v = *(const f32x4*)(etf + c * 132 + q);
    const long xi = ((long)(b * 64 + c) << 10) + s0 + q;
    const f32x4 xv = *(const f32x4*)(x + xi);
    #pragma unroll
    for (int e = 0; e < 4; e++) v[e] += bias + xv[e];
    *(f32x4*)(out + xi) = v;
  }
}

// ---------------------------------------------------------------------------
extern "C" void kernel_launch(void* const* d_in, const int* in_sizes, int n_in,
                              void* d_out, int out_size, void* d_ws, size_t ws_size,
                              hipStream_t stream)
{
  (void)in_sizes; (void)n_in; (void)out_size; (void)ws_size;
  const float* x  = (const float*)d_in[0];
  // d_in[1] = t (unused)
  const float* Wp = (const float*)d_in[2];
  const float* bp = (const float*)d_in[3];
  const float* Wo = (const float*)d_in[4];
  const float* bo = (const float*)d_in[5];
  float* out = (float*)d_out;

  char* w8 = (char*)d_ws;
  u16*   xt   = (u16*)(w8 + 0L);          // [8192][64] bf16, 1 MB
  u16*   xb   = (u16*)(w8 + 1048576L);    // [8][80][1024] bf16, 1.25 MB
  u16*   Wot  = (u16*)(w8 + 2359296L);    // [64][2560] bf16
  u16*   Wpb  = (u16*)(w8 + 2686976L);    // [64][7680] bf16
  u16*   Ahat = (u16*)(w8 + 3670016L);    // [4][64][64] bf16
  u16*   MxT  = (u16*)(w8 + 3702784L);    // [64][320] bf16
  float* uh   = (float*)(w8 + 3743744L);  // [4][64]
  float* Z    = (float*)(w8 + 3744768L);  // [32][1024] f32
  u16*   G    = (u16*)(w8 + 3875840L);    // [8192][320] bf16, 5 MB

  k_misc<<<792, 256, 0, stream>>>(x, Wp, Wo, bp, xt, Wot, Wpb, xb, uh);
  k_nh  <<<64,  256, 0, stream>>>(Wot, bp, MxT);
  k_prep<<<8,   256, 0, stream>>>(Wpb, Wot, Ahat, MxT);
  k_qkz <<<256, 256, 0, stream>>>(xt, Ahat, uh, Z);
  k_G   <<<256, 256, 0, stream>>>(xt, xb, Ahat, uh, Z, G);
  k_out <<<64,  256, 0, stream>>>(G, MxT, bo, x, out);
}